// Round 6
// baseline (382.214 us; speedup 1.0000x reference)
//
#include <hip/hip_runtime.h>
#include <math.h>

#define N_NODES 50000
#define E_RAW 800000
#define E_TOT 850000
#define NEG_SLOPE 0.2f
#define NBLK ((N_NODES + 1023) / 1024)

__device__ __forceinline__ float lrelu(float a) { return a > 0.f ? a : NEG_SLOPE * a; }

__device__ __forceinline__ unsigned short f2bf(float f) {
    unsigned u = __float_as_uint(f);
    return (unsigned short)((u + 0x7fff + ((u >> 16) & 1)) >> 16);
}
__device__ __forceinline__ float bflo(unsigned p) { return __uint_as_float(p << 16); }
__device__ __forceinline__ float bfhi(unsigned p) { return __uint_as_float(p & 0xffff0000u); }

// ---------------- CSR build (dst-major) ----------------
__global__ void k_deg(const int* __restrict__ ei, int* __restrict__ deg) {
    int e = blockIdx.x * blockDim.x + threadIdx.x;
    if (e >= E_TOT) return;
    int col = (e < E_RAW) ? ei[E_RAW + e] : (e - E_RAW);
    atomicAdd(&deg[col], 1);
}

__global__ void k_scan1(const int* __restrict__ deg, int* __restrict__ off, int* __restrict__ blksum) {
    __shared__ int sh[1024];
    int b = blockIdx.x;
    int i = b * 1024 + threadIdx.x;
    int v = (i < N_NODES) ? deg[i] : 0;
    sh[threadIdx.x] = v;
    __syncthreads();
    for (int ofs = 1; ofs < 1024; ofs <<= 1) {
        int t = (threadIdx.x >= ofs) ? sh[threadIdx.x - ofs] : 0;
        __syncthreads();
        sh[threadIdx.x] += t;
        __syncthreads();
    }
    if (i < N_NODES) off[i] = sh[threadIdx.x] - v;
    if (threadIdx.x == 1023) blksum[b] = sh[1023];
}

__global__ void k_scan2(const int* __restrict__ blksum, int* __restrict__ blkoff, int* __restrict__ off) {
    int l = threadIdx.x & 63;
    int v = (l < NBLK) ? blksum[l] : 0;
    int incl = v;
    for (int ofs = 1; ofs < 64; ofs <<= 1) {
        int t = __shfl_up(incl, ofs);
        if (l >= ofs) incl += t;
    }
    if (l < NBLK) blkoff[l] = incl - v;
    if (l == 63) off[N_NODES] = incl;
}

__global__ void k_scan3(int* __restrict__ off, const int* __restrict__ blkoff, int* __restrict__ cur) {
    int i = blockIdx.x * blockDim.x + threadIdx.x;
    if (i >= N_NODES) return;
    int v = off[i] + blkoff[i >> 10];
    off[i] = v;
    cur[i] = v;
}

__global__ void k_scatter(const int* __restrict__ ei, int* __restrict__ cur, int* __restrict__ srcs) {
    int e = blockIdx.x * blockDim.x + threadIdx.x;
    if (e >= E_TOT) return;
    int row, col;
    if (e < E_RAW) { row = ei[e]; col = ei[E_RAW + e]; }
    else { row = e - E_RAW; col = row; }
    int pos = atomicAdd(&cur[col], 1);
    srcs[pos] = row;
}

// ---------------- GEMM 1: h1 = x @ W1, bf16 out + attn1 epilogue ----------------
// block = 64 threads (1 wave), 16 rows/block, 2 cols/thread (cols 2j, 2j+1).
// A reads are wave-uniform -> s_load (scalar cache), no LDS.
__global__ void k_gemm1(const float* __restrict__ A, const float* __restrict__ B,
                        const float* __restrict__ aux, unsigned* __restrict__ C,
                        float* __restrict__ es, float* __restrict__ ed) {
    constexpr int MT = 16, K = 128;
    int m0 = blockIdx.x * MT;
    int j = threadIdx.x;   // 0..63
    float accx[MT], accy[MT];
#pragma unroll
    for (int m = 0; m < MT; ++m) { accx[m] = 0.f; accy[m] = 0.f; }
    const float2* B2 = (const float2*)B;   // row k: 64 float2
#pragma unroll 4
    for (int k = 0; k < K; ++k) {
        float2 b = B2[k * 64 + j];
#pragma unroll
        for (int m = 0; m < MT; ++m) {
            float a = A[(size_t)(m0 + m) * K + k];   // uniform -> s_load
            accx[m] = fmaf(a, b.x, accx[m]);
            accy[m] = fmaf(a, b.y, accy[m]);
        }
    }
    // bf16 pack: feats 2j (lo), 2j+1 (hi) -> matches agg1 layout
#pragma unroll
    for (int m = 0; m < MT; ++m) {
        unsigned lo = f2bf(accx[m]), hi = f2bf(accy[m]);
        C[(size_t)(m0 + m) * 64 + j] = lo | (hi << 16);
    }
    // attn1 epilogue: head h = j>>4 (16-lane group covers 32 feats), f0 = j&15
    int f0 = j & 15, h = j >> 4;
    float al0 = aux[h * 64 + 2 * f0], al1 = aux[h * 64 + 2 * f0 + 1];
    float ar0 = aux[h * 64 + 32 + 2 * f0], ar1 = aux[h * 64 + 32 + 2 * f0 + 1];
#pragma unroll
    for (int m = 0; m < MT; ++m) {
        float pl = accx[m] * al0 + accy[m] * al1;
        float pr = accx[m] * ar0 + accy[m] * ar1;
#pragma unroll
        for (int mask = 8; mask; mask >>= 1) { pl += __shfl_xor(pl, mask); pr += __shfl_xor(pr, mask); }
        if (f0 == 0) { es[(m0 + m) * 4 + h] = pl; ed[(m0 + m) * 4 + h] = pr; }
    }
}

// ---------------- GEMM 2: h2 = out1 @ W2, bf16 out + attn2 epilogue ----------------
// block = 64 threads, 16 rows/block, 1 col/thread. K=128, NC=64.
__global__ void k_gemm2(const float* __restrict__ A, const float* __restrict__ B,
                        const float* __restrict__ aux, unsigned short* __restrict__ C,
                        float* __restrict__ es, float* __restrict__ ed) {
    constexpr int MT = 16, K = 128, NC = 64;
    int m0 = blockIdx.x * MT;
    int j = threadIdx.x;
    float acc[MT];
#pragma unroll
    for (int m = 0; m < MT; ++m) acc[m] = 0.f;
#pragma unroll 4
    for (int k = 0; k < K; ++k) {
        float b = B[k * NC + j];
#pragma unroll
        for (int m = 0; m < MT; ++m)
            acc[m] = fmaf(A[(size_t)(m0 + m) * K + k], b, acc[m]);
    }
#pragma unroll
    for (int m = 0; m < MT; ++m) C[(size_t)(m0 + m) * NC + j] = f2bf(acc[m]);
    float al = aux[j], ar = aux[64 + j];
#pragma unroll
    for (int m = 0; m < MT; ++m) {
        float pl = acc[m] * al, pr = acc[m] * ar;
#pragma unroll
        for (int mask = 32; mask; mask >>= 1) { pl += __shfl_xor(pl, mask); pr += __shfl_xor(pr, mask); }
        if (j == 0) { es[m0 + m] = pl; ed[m0 + m] = pr; }
    }
}

// ---------------- GEMM 3 (head): out = h2agg @ headW + b, fp32 out ----------------
__global__ void k_gemm3(const float* __restrict__ A, const float* __restrict__ B,
                        const float* __restrict__ bias, float* __restrict__ C) {
    constexpr int MT = 16, K = 64, NC = 64;
    int m0 = blockIdx.x * MT;
    int j = threadIdx.x;
    float acc[MT];
#pragma unroll
    for (int m = 0; m < MT; ++m) acc[m] = 0.f;
#pragma unroll 4
    for (int k = 0; k < K; ++k) {
        float b = B[k * NC + j];
#pragma unroll
        for (int m = 0; m < MT; ++m)
            acc[m] = fmaf(A[(size_t)(m0 + m) * K + k], b, acc[m]);
    }
    float bv = bias[j];
#pragma unroll
    for (int m = 0; m < MT; ++m) C[(size_t)(m0 + m) * NC + j] = acc[m] + bv;
}

// ---------------- layer-1 fused softmax+aggregate: one wave per node ----------------
__global__ void k_agg1(const unsigned* __restrict__ h1b, const float* __restrict__ es,
                       const float* __restrict__ ed, const int* __restrict__ off,
                       const int* __restrict__ srcs, float* __restrict__ out1) {
    int n = blockIdx.x * (blockDim.x >> 6) + (threadIdx.x >> 6);
    int lane = threadIdx.x & 63;
    if (n >= N_NODES) return;
    int myh = lane & 3;
    float edh = ed[n * 4 + myh];
    int hc = lane >> 4;
    int s = off[n], e = off[n + 1];
    int jj = lane >> 2;
    float ax = 0.f, ay = 0.f, psum = 0.f;
    for (int base = s; base < e; base += 16) {
        int cnt = e - base;
        int srcj = 0;
        float w = 0.f;
        if (jj < cnt) {
            srcj = srcs[base + jj];
            w = __expf(lrelu(es[srcj * 4 + myh] + edh));
        }
        psum += w;
#pragma unroll
        for (int j2 = 0; j2 < 16; ++j2) {
            int src = __shfl(srcj, j2 * 4);
            float wc = __shfl(w, j2 * 4 + hc);
            unsigned p = h1b[(size_t)src * 64 + lane];
            ax = fmaf(bflo(p), wc, ax);
            ay = fmaf(bfhi(p), wc, ay);
        }
    }
#pragma unroll
    for (int mask = 4; mask <= 32; mask <<= 1) psum += __shfl_xor(psum, mask);
    float inv = 1.f / __shfl(psum, hc);
    float2 o;
    o.x = fmaxf(ax * inv, 0.f);
    o.y = fmaxf(ay * inv, 0.f);
    ((float2*)out1)[(size_t)n * 64 + lane] = o;
}

// ---------------- layer-2 fused softmax+aggregate: half-wave per node ----------------
__global__ void k_agg2(const unsigned* __restrict__ h2b, const float* __restrict__ es,
                       const float* __restrict__ ed, const int* __restrict__ off,
                       const int* __restrict__ srcs, float* __restrict__ outv) {
    int n = blockIdx.x * (blockDim.x >> 5) + (threadIdx.x >> 5);
    int l = threadIdx.x & 31;
    int hb = threadIdx.x & 32;
    if (n >= N_NODES) return;
    float edv = ed[n];
    int s = off[n], e = off[n + 1];
    float ax = 0.f, ay = 0.f, psum = 0.f;
    for (int base = s; base < e; base += 32) {
        int cnt = e - base;
        int srcj = 0;
        float w = 0.f;
        if (l < cnt) {
            srcj = srcs[base + l];
            w = __expf(lrelu(es[srcj] + edv));
        }
        psum += w;
#pragma unroll
        for (int j = 0; j < 32; ++j) {
            int src = __shfl(srcj, hb + j);
            float wj = __shfl(w, hb + j);
            unsigned p = h2b[(size_t)src * 32 + l];
            ax = fmaf(bflo(p), wj, ax);
            ay = fmaf(bfhi(p), wj, ay);
        }
    }
#pragma unroll
    for (int mask = 1; mask <= 16; mask <<= 1) psum += __shfl_xor(psum, mask);
    float inv = 1.f / psum;
    float2 o; o.x = ax * inv; o.y = ay * inv;
    ((float2*)outv)[(size_t)n * 32 + l] = o;
}

extern "C" void kernel_launch(void* const* d_in, const int* in_sizes, int n_in,
                              void* d_out, int out_size, void* d_ws, size_t ws_size,
                              hipStream_t stream) {
    const float* x     = (const float*)d_in[0];
    const int*   ei    = (const int*)d_in[1];
    const float* W1    = (const float*)d_in[2];
    const float* attn1 = (const float*)d_in[3];
    const float* W2    = (const float*)d_in[4];
    const float* attn2 = (const float*)d_in[5];
    const float* headW = (const float*)d_in[6];
    const float* headb = (const float*)d_in[7];
    float* out = (float*)d_out;

    char* ws = (char*)d_ws;
    size_t o = 0;
    auto alloc = [&](size_t bytes) -> void* {
        o = (o + 255) & ~(size_t)255;
        void* p = ws + o;
        o += bytes;
        return p;
    };
    unsigned* h1b    = (unsigned*)alloc((size_t)N_NODES * 128 * 2);
    float*    out1   = (float*)alloc((size_t)N_NODES * 128 * 4);
    unsigned* h2b    = (unsigned*)alloc((size_t)N_NODES * 64 * 2);
    float*    h2agg  = (float*)alloc((size_t)N_NODES * 64 * 4);
    float*    e1s    = (float*)alloc((size_t)N_NODES * 4 * 4);
    float*    e1d    = (float*)alloc((size_t)N_NODES * 4 * 4);
    float*    e2s    = (float*)alloc((size_t)N_NODES * 4);
    float*    e2d    = (float*)alloc((size_t)N_NODES * 4);
    int*      deg    = (int*)alloc((size_t)N_NODES * 4);
    int*      off    = (int*)alloc((size_t)(N_NODES + 1) * 4);
    int*      cur    = (int*)alloc((size_t)N_NODES * 4);
    int*      srcs   = (int*)alloc((size_t)E_TOT * 4);
    int*      blksum = (int*)alloc((size_t)NBLK * 4);
    int*      blkoff = (int*)alloc((size_t)NBLK * 4);

    // CSR build
    (void)hipMemsetAsync(deg, 0, (size_t)N_NODES * 4, stream);
    k_deg<<<(E_TOT + 255) / 256, 256, 0, stream>>>(ei, deg);
    k_scan1<<<NBLK, 1024, 0, stream>>>(deg, off, blksum);
    k_scan2<<<1, 64, 0, stream>>>(blksum, blkoff, off);
    k_scan3<<<(N_NODES + 255) / 256, 256, 0, stream>>>(off, blkoff, cur);
    k_scatter<<<(E_TOT + 255) / 256, 256, 0, stream>>>(ei, cur, srcs);

    // layer 1
    k_gemm1<<<N_NODES / 16, 64, 0, stream>>>(x, W1, attn1, h1b, e1s, e1d);
    k_agg1<<<N_NODES / 4, 256, 0, stream>>>(h1b, e1s, e1d, off, srcs, out1);

    // layer 2
    k_gemm2<<<N_NODES / 16, 64, 0, stream>>>(out1, W2, attn2, (unsigned short*)h2b, e2s, e2d);
    k_agg2<<<N_NODES / 8, 256, 0, stream>>>(h2b, e2s, e2d, off, srcs, h2agg);

    // head
    k_gemm3<<<N_NODES / 16, 64, 0, stream>>>(h2agg, headW, headb, out);
}

// Round 7
// 323.027 us; speedup vs baseline: 1.1832x; 1.1832x over previous
//
#include <hip/hip_runtime.h>
#include <math.h>

#define N_NODES 50000
#define E_RAW 800000
#define E_TOT 850000
#define NEG_SLOPE 0.2f
#define NBLK ((N_NODES + 1023) / 1024)

__device__ __forceinline__ float lrelu(float a) { return a > 0.f ? a : NEG_SLOPE * a; }

__device__ __forceinline__ unsigned f2bf(float f) {
    unsigned u = __float_as_uint(f);
    return (u + 0x7fff + ((u >> 16) & 1)) >> 16;
}
__device__ __forceinline__ unsigned pack2(float a, float b) {
    return f2bf(a) | (f2bf(b) << 16);
}
__device__ __forceinline__ float bflo(unsigned p) { return __uint_as_float(p << 16); }
__device__ __forceinline__ float bfhi(unsigned p) { return __uint_as_float(p & 0xffff0000u); }

// ---------------- CSR build (dst-major) ----------------
__global__ void k_deg(const int* __restrict__ ei, int* __restrict__ deg) {
    int e = blockIdx.x * blockDim.x + threadIdx.x;
    if (e >= E_TOT) return;
    int col = (e < E_RAW) ? ei[E_RAW + e] : (e - E_RAW);
    atomicAdd(&deg[col], 1);
}

__global__ void k_scan1(const int* __restrict__ deg, int* __restrict__ off, int* __restrict__ blksum) {
    __shared__ int sh[1024];
    int b = blockIdx.x;
    int i = b * 1024 + threadIdx.x;
    int v = (i < N_NODES) ? deg[i] : 0;
    sh[threadIdx.x] = v;
    __syncthreads();
    for (int ofs = 1; ofs < 1024; ofs <<= 1) {
        int t = (threadIdx.x >= ofs) ? sh[threadIdx.x - ofs] : 0;
        __syncthreads();
        sh[threadIdx.x] += t;
        __syncthreads();
    }
    if (i < N_NODES) off[i] = sh[threadIdx.x] - v;
    if (threadIdx.x == 1023) blksum[b] = sh[1023];
}

__global__ void k_scan2(const int* __restrict__ blksum, int* __restrict__ blkoff, int* __restrict__ off) {
    int l = threadIdx.x & 63;
    int v = (l < NBLK) ? blksum[l] : 0;
    int incl = v;
    for (int ofs = 1; ofs < 64; ofs <<= 1) {
        int t = __shfl_up(incl, ofs);
        if (l >= ofs) incl += t;
    }
    if (l < NBLK) blkoff[l] = incl - v;
    if (l == 63) off[N_NODES] = incl;
}

__global__ void k_scan3(int* __restrict__ off, const int* __restrict__ blkoff, int* __restrict__ cur) {
    int i = blockIdx.x * blockDim.x + threadIdx.x;
    if (i >= N_NODES) return;
    int v = off[i] + blkoff[i >> 10];
    off[i] = v;
    cur[i] = v;
}

__global__ void k_scatter(const int* __restrict__ ei, int* __restrict__ cur, int* __restrict__ srcs) {
    int e = blockIdx.x * blockDim.x + threadIdx.x;
    if (e >= E_TOT) return;
    int row, col;
    if (e < E_RAW) { row = ei[e]; col = ei[E_RAW + e]; }
    else { row = e - E_RAW; col = row; }
    int pos = atomicAdd(&cur[col], 1);
    srcs[pos] = row;
}

// ---------------- GEMM 1: h1 = x @ W1 (K=128, NC=128), bf16 out + attn1 ----------------
// block 64 = 2 row-groups(8 rows) x 32 lanes; 4 cols/thread (cols 4l..4l+3).
// A staged in LDS; per ds_read_b128 (2-addr, free) -> 16 FMAs/thread.
__global__ void k_gemm1(const float* __restrict__ A, const float* __restrict__ B,
                        const float* __restrict__ aux, uint2* __restrict__ C,
                        float* __restrict__ es, float* __restrict__ ed) {
    constexpr int K = 128, MT = 16;
    __shared__ float As[MT * K];   // 8 KB
    int m0 = blockIdx.x * MT;
    int t = threadIdx.x, g = t >> 5, l = t & 31;
    const float4* A4 = (const float4*)(A + (size_t)m0 * K);
    float4* S4 = (float4*)As;
#pragma unroll
    for (int i = 0; i < 8; ++i) S4[t + 64 * i] = A4[t + 64 * i];
    __syncthreads();
    float acc[8][4];
#pragma unroll
    for (int r = 0; r < 8; ++r)
#pragma unroll
        for (int c = 0; c < 4; ++c) acc[r][c] = 0.f;
    const float4* B4 = (const float4*)B;   // row k = 32 float4
    for (int kk = 0; kk < K / 4; ++kk) {
        float4 b0 = B4[(4 * kk + 0) * 32 + l];
        float4 b1 = B4[(4 * kk + 1) * 32 + l];
        float4 b2 = B4[(4 * kk + 2) * 32 + l];
        float4 b3 = B4[(4 * kk + 3) * 32 + l];
#pragma unroll
        for (int r = 0; r < 8; ++r) {
            float4 a = ((const float4*)(As + (g * 8 + r) * K))[kk];
            acc[r][0] = fmaf(a.x, b0.x, fmaf(a.y, b1.x, fmaf(a.z, b2.x, fmaf(a.w, b3.x, acc[r][0]))));
            acc[r][1] = fmaf(a.x, b0.y, fmaf(a.y, b1.y, fmaf(a.z, b2.y, fmaf(a.w, b3.y, acc[r][1]))));
            acc[r][2] = fmaf(a.x, b0.z, fmaf(a.y, b1.z, fmaf(a.z, b2.z, fmaf(a.w, b3.z, acc[r][2]))));
            acc[r][3] = fmaf(a.x, b0.w, fmaf(a.y, b1.w, fmaf(a.z, b2.w, fmaf(a.w, b3.w, acc[r][3]))));
        }
    }
    // bf16 store: cols (4l,4l+1),(4l+2,4l+3) -> u32 pairs 2l, 2l+1 of 64-u32 row
#pragma unroll
    for (int r = 0; r < 8; ++r) {
        int row = m0 + g * 8 + r;
        uint2 v; v.x = pack2(acc[r][0], acc[r][1]); v.y = pack2(acc[r][2], acc[r][3]);
        C[(size_t)row * 32 + l] = v;
    }
    // attn1 epilogue: head h = l>>3 (cols 4l..4l+3 all in head h), col-in-head = 4*(l&7)+c
    int h = l >> 3, f0 = 4 * (l & 7);
    float al0 = aux[h * 64 + f0], al1 = aux[h * 64 + f0 + 1], al2 = aux[h * 64 + f0 + 2], al3 = aux[h * 64 + f0 + 3];
    float ar0 = aux[h * 64 + 32 + f0], ar1 = aux[h * 64 + 32 + f0 + 1], ar2 = aux[h * 64 + 32 + f0 + 2], ar3 = aux[h * 64 + 32 + f0 + 3];
#pragma unroll
    for (int r = 0; r < 8; ++r) {
        float pl = acc[r][0] * al0 + acc[r][1] * al1 + acc[r][2] * al2 + acc[r][3] * al3;
        float pr = acc[r][0] * ar0 + acc[r][1] * ar1 + acc[r][2] * ar2 + acc[r][3] * ar3;
#pragma unroll
        for (int mask = 4; mask; mask >>= 1) { pl += __shfl_xor(pl, mask); pr += __shfl_xor(pr, mask); }
        if ((l & 7) == 0) {
            int row = m0 + g * 8 + r;
            es[row * 4 + h] = pl; ed[row * 4 + h] = pr;
        }
    }
}

// ---------------- GEMM 2/3: NC=64. block 64 = 4 row-groups(8 rows) x 16 lanes, 4 cols/thread ----------------
// EPI 2: attn2 epilogue + bf16 out (uint2*). EPI 3: +bias, fp32 out (float4*).
template<int K, int EPI>
__global__ void k_gemm23(const float* __restrict__ A, const float* __restrict__ B,
                         const float* __restrict__ aux, void* __restrict__ Cv,
                         float* __restrict__ es, float* __restrict__ ed) {
    constexpr int MT = 32;
    __shared__ float As[MT * K];
    int m0 = blockIdx.x * MT;
    int t = threadIdx.x, g = t >> 4, l = t & 15;
    int rows = min(MT, N_NODES - m0);
    const float4* A4 = (const float4*)(A + (size_t)m0 * K);
    float4* S4 = (float4*)As;
    for (int i = t; i < rows * (K / 4); i += 64) S4[i] = A4[i];
    __syncthreads();
    float acc[8][4];
#pragma unroll
    for (int r = 0; r < 8; ++r)
#pragma unroll
        for (int c = 0; c < 4; ++c) acc[r][c] = 0.f;
    const float4* B4 = (const float4*)B;   // row k = 16 float4
    for (int kk = 0; kk < K / 4; ++kk) {
        float4 b0 = B4[(4 * kk + 0) * 16 + l];
        float4 b1 = B4[(4 * kk + 1) * 16 + l];
        float4 b2 = B4[(4 * kk + 2) * 16 + l];
        float4 b3 = B4[(4 * kk + 3) * 16 + l];
#pragma unroll
        for (int r = 0; r < 8; ++r) {
            float4 a = ((const float4*)(As + (g * 8 + r) * K))[kk];
            acc[r][0] = fmaf(a.x, b0.x, fmaf(a.y, b1.x, fmaf(a.z, b2.x, fmaf(a.w, b3.x, acc[r][0]))));
            acc[r][1] = fmaf(a.x, b0.y, fmaf(a.y, b1.y, fmaf(a.z, b2.y, fmaf(a.w, b3.y, acc[r][1]))));
            acc[r][2] = fmaf(a.x, b0.z, fmaf(a.y, b1.z, fmaf(a.z, b2.z, fmaf(a.w, b3.z, acc[r][2]))));
            acc[r][3] = fmaf(a.x, b0.w, fmaf(a.y, b1.w, fmaf(a.z, b2.w, fmaf(a.w, b3.w, acc[r][3]))));
        }
    }
    if (EPI == 2) {
        uint2* C = (uint2*)Cv;
        float al0 = aux[4 * l], al1 = aux[4 * l + 1], al2 = aux[4 * l + 2], al3 = aux[4 * l + 3];
        float ar0 = aux[64 + 4 * l], ar1 = aux[64 + 4 * l + 1], ar2 = aux[64 + 4 * l + 2], ar3 = aux[64 + 4 * l + 3];
#pragma unroll
        for (int r = 0; r < 8; ++r) {
            int row = m0 + g * 8 + r;
            float pl = acc[r][0] * al0 + acc[r][1] * al1 + acc[r][2] * al2 + acc[r][3] * al3;
            float pr = acc[r][0] * ar0 + acc[r][1] * ar1 + acc[r][2] * ar2 + acc[r][3] * ar3;
#pragma unroll
            for (int mask = 8; mask; mask >>= 1) { pl += __shfl_xor(pl, mask); pr += __shfl_xor(pr, mask); }
            if (row < N_NODES) {
                uint2 v; v.x = pack2(acc[r][0], acc[r][1]); v.y = pack2(acc[r][2], acc[r][3]);
                C[(size_t)row * 16 + l] = v;
                if (l == 0) { es[row] = pl; ed[row] = pr; }
            }
        }
    } else {
        float4* C = (float4*)Cv;
        float4 bv = ((const float4*)aux)[l];
#pragma unroll
        for (int r = 0; r < 8; ++r) {
            int row = m0 + g * 8 + r;
            if (row < N_NODES) {
                float4 v;
                v.x = acc[r][0] + bv.x; v.y = acc[r][1] + bv.y;
                v.z = acc[r][2] + bv.z; v.w = acc[r][3] + bv.w;
                C[(size_t)row * 16 + l] = v;
            }
        }
    }
}

// ---------------- layer-1 fused softmax+aggregate: one wave per node ----------------
__global__ void k_agg1(const unsigned* __restrict__ h1b, const float* __restrict__ es,
                       const float* __restrict__ ed, const int* __restrict__ off,
                       const int* __restrict__ srcs, float* __restrict__ out1) {
    int n = blockIdx.x * (blockDim.x >> 6) + (threadIdx.x >> 6);
    int lane = threadIdx.x & 63;
    if (n >= N_NODES) return;
    int myh = lane & 3;
    float edh = ed[n * 4 + myh];
    int hc = lane >> 4;
    int s = off[n], e = off[n + 1];
    int jj = lane >> 2;
    float ax = 0.f, ay = 0.f, psum = 0.f;
    for (int base = s; base < e; base += 16) {
        int cnt = e - base;
        int srcj = 0;
        float w = 0.f;
        if (jj < cnt) {
            srcj = srcs[base + jj];
            w = __expf(lrelu(es[srcj * 4 + myh] + edh));
        }
        psum += w;
#pragma unroll
        for (int j2 = 0; j2 < 16; ++j2) {
            int src = __shfl(srcj, j2 * 4);
            float wc = __shfl(w, j2 * 4 + hc);
            unsigned p = h1b[(size_t)src * 64 + lane];
            ax = fmaf(bflo(p), wc, ax);
            ay = fmaf(bfhi(p), wc, ay);
        }
    }
#pragma unroll
    for (int mask = 4; mask <= 32; mask <<= 1) psum += __shfl_xor(psum, mask);
    float inv = 1.f / __shfl(psum, hc);
    float2 o;
    o.x = fmaxf(ax * inv, 0.f);
    o.y = fmaxf(ay * inv, 0.f);
    ((float2*)out1)[(size_t)n * 64 + lane] = o;
}

// ---------------- layer-2 fused softmax+aggregate: half-wave per node ----------------
__global__ void k_agg2(const unsigned* __restrict__ h2b, const float* __restrict__ es,
                       const float* __restrict__ ed, const int* __restrict__ off,
                       const int* __restrict__ srcs, float* __restrict__ outv) {
    int n = blockIdx.x * (blockDim.x >> 5) + (threadIdx.x >> 5);
    int l = threadIdx.x & 31;
    int hb = threadIdx.x & 32;
    if (n >= N_NODES) return;
    float edv = ed[n];
    int s = off[n], e = off[n + 1];
    float ax = 0.f, ay = 0.f, psum = 0.f;
    for (int base = s; base < e; base += 32) {
        int cnt = e - base;
        int srcj = 0;
        float w = 0.f;
        if (l < cnt) {
            srcj = srcs[base + l];
            w = __expf(lrelu(es[srcj] + edv));
        }
        psum += w;
#pragma unroll
        for (int j = 0; j < 32; ++j) {
            int src = __shfl(srcj, hb + j);
            float wj = __shfl(w, hb + j);
            unsigned p = h2b[(size_t)src * 32 + l];
            ax = fmaf(bflo(p), wj, ax);
            ay = fmaf(bfhi(p), wj, ay);
        }
    }
#pragma unroll
    for (int mask = 1; mask <= 16; mask <<= 1) psum += __shfl_xor(psum, mask);
    float inv = 1.f / psum;
    float2 o; o.x = ax * inv; o.y = ay * inv;
    ((float2*)outv)[(size_t)n * 32 + l] = o;
}

extern "C" void kernel_launch(void* const* d_in, const int* in_sizes, int n_in,
                              void* d_out, int out_size, void* d_ws, size_t ws_size,
                              hipStream_t stream) {
    const float* x     = (const float*)d_in[0];
    const int*   ei    = (const int*)d_in[1];
    const float* W1    = (const float*)d_in[2];
    const float* attn1 = (const float*)d_in[3];
    const float* W2    = (const float*)d_in[4];
    const float* attn2 = (const float*)d_in[5];
    const float* headW = (const float*)d_in[6];
    const float* headb = (const float*)d_in[7];
    float* out = (float*)d_out;

    char* ws = (char*)d_ws;
    size_t o = 0;
    auto alloc = [&](size_t bytes) -> void* {
        o = (o + 255) & ~(size_t)255;
        void* p = ws + o;
        o += bytes;
        return p;
    };
    unsigned* h1b    = (unsigned*)alloc((size_t)N_NODES * 128 * 2);
    float*    out1   = (float*)alloc((size_t)N_NODES * 128 * 4);
    unsigned* h2b    = (unsigned*)alloc((size_t)N_NODES * 64 * 2);
    float*    h2agg  = (float*)alloc((size_t)N_NODES * 64 * 4);
    float*    e1s    = (float*)alloc((size_t)N_NODES * 4 * 4);
    float*    e1d    = (float*)alloc((size_t)N_NODES * 4 * 4);
    float*    e2s    = (float*)alloc((size_t)N_NODES * 4);
    float*    e2d    = (float*)alloc((size_t)N_NODES * 4);
    int*      deg    = (int*)alloc((size_t)N_NODES * 4);
    int*      off    = (int*)alloc((size_t)(N_NODES + 1) * 4);
    int*      cur    = (int*)alloc((size_t)N_NODES * 4);
    int*      srcs   = (int*)alloc((size_t)E_TOT * 4);
    int*      blksum = (int*)alloc((size_t)NBLK * 4);
    int*      blkoff = (int*)alloc((size_t)NBLK * 4);

    // CSR build
    (void)hipMemsetAsync(deg, 0, (size_t)N_NODES * 4, stream);
    k_deg<<<(E_TOT + 255) / 256, 256, 0, stream>>>(ei, deg);
    k_scan1<<<NBLK, 1024, 0, stream>>>(deg, off, blksum);
    k_scan2<<<1, 64, 0, stream>>>(blksum, blkoff, off);
    k_scan3<<<(N_NODES + 255) / 256, 256, 0, stream>>>(off, blkoff, cur);
    k_scatter<<<(E_TOT + 255) / 256, 256, 0, stream>>>(ei, cur, srcs);

    // layer 1
    k_gemm1<<<N_NODES / 16, 64, 0, stream>>>(x, W1, attn1, (uint2*)h1b, e1s, e1d);
    k_agg1<<<N_NODES / 4, 256, 0, stream>>>(h1b, e1s, e1d, off, srcs, out1);

    // layer 2
    k_gemm23<128, 2><<<(N_NODES + 31) / 32, 64, 0, stream>>>(out1, W2, attn2, h2b, e2s, e2d);
    k_agg2<<<N_NODES / 8, 256, 0, stream>>>(h2b, e2s, e2d, off, srcs, h2agg);

    // head
    k_gemm23<64, 3><<<(N_NODES + 31) / 32, 64, 0, stream>>>(h2agg, headW, headb, out, nullptr, nullptr);
}

// Round 8
// 311.467 us; speedup vs baseline: 1.2271x; 1.0371x over previous
//
#include <hip/hip_runtime.h>
#include <math.h>

#define N_NODES 50000
#define E_RAW 800000
#define E_TOT 850000
#define NEG_SLOPE 0.2f
#define NBLK ((N_NODES + 1023) / 1024)

__device__ __forceinline__ float lrelu(float a) { return a > 0.f ? a : NEG_SLOPE * a; }

__device__ __forceinline__ unsigned f2bf(float f) {
    unsigned u = __float_as_uint(f);
    return (u + 0x7fff + ((u >> 16) & 1)) >> 16;
}
__device__ __forceinline__ unsigned pack2(float a, float b) {
    return f2bf(a) | (f2bf(b) << 16);
}
__device__ __forceinline__ float bflo(unsigned p) { return __uint_as_float(p << 16); }
__device__ __forceinline__ float bfhi(unsigned p) { return __uint_as_float(p & 0xffff0000u); }

// ---------------- CSR build (dst-major), 4 edges/thread for atomic ILP ----------------
__global__ void k_deg(const int* __restrict__ ei, int* __restrict__ deg) {
    int t = blockIdx.x * blockDim.x + threadIdx.x;
    int e0 = 4 * t;
    if (e0 >= E_TOT) return;
    int col[4];
    if (e0 + 3 < E_RAW) {
        int4 c4 = ((const int4*)(ei + E_RAW))[t];
        col[0] = c4.x; col[1] = c4.y; col[2] = c4.z; col[3] = c4.w;
    } else {
#pragma unroll
        for (int i = 0; i < 4; ++i) {
            int e = e0 + i;
            col[i] = (e < E_RAW) ? ei[E_RAW + e] : (e - E_RAW);
        }
    }
#pragma unroll
    for (int i = 0; i < 4; ++i)
        if (e0 + i < E_TOT) atomicAdd(&deg[col[i]], 1);
}

__global__ void k_scan1(const int* __restrict__ deg, int* __restrict__ off, int* __restrict__ blksum) {
    __shared__ int sh[1024];
    int b = blockIdx.x;
    int i = b * 1024 + threadIdx.x;
    int v = (i < N_NODES) ? deg[i] : 0;
    sh[threadIdx.x] = v;
    __syncthreads();
    for (int ofs = 1; ofs < 1024; ofs <<= 1) {
        int t = (threadIdx.x >= ofs) ? sh[threadIdx.x - ofs] : 0;
        __syncthreads();
        sh[threadIdx.x] += t;
        __syncthreads();
    }
    if (i < N_NODES) off[i] = sh[threadIdx.x] - v;
    if (threadIdx.x == 1023) blksum[b] = sh[1023];
}

__global__ void k_scan2(const int* __restrict__ blksum, int* __restrict__ blkoff, int* __restrict__ off) {
    int l = threadIdx.x & 63;
    int v = (l < NBLK) ? blksum[l] : 0;
    int incl = v;
    for (int ofs = 1; ofs < 64; ofs <<= 1) {
        int t = __shfl_up(incl, ofs);
        if (l >= ofs) incl += t;
    }
    if (l < NBLK) blkoff[l] = incl - v;
    if (l == 63) off[N_NODES] = incl;
}

__global__ void k_scan3(int* __restrict__ off, const int* __restrict__ blkoff, int* __restrict__ cur) {
    int i = blockIdx.x * blockDim.x + threadIdx.x;
    if (i >= N_NODES) return;
    int v = off[i] + blkoff[i >> 10];
    off[i] = v;
    cur[i] = v;
}

__global__ void k_scatter(const int* __restrict__ ei, int* __restrict__ cur,
                          unsigned short* __restrict__ srcs) {
    int t = blockIdx.x * blockDim.x + threadIdx.x;
    int e0 = 4 * t;
    if (e0 >= E_TOT) return;
    int row[4], col[4];
    if (e0 + 3 < E_RAW) {
        int4 r4 = ((const int4*)ei)[t];
        int4 c4 = ((const int4*)(ei + E_RAW))[t];
        row[0] = r4.x; row[1] = r4.y; row[2] = r4.z; row[3] = r4.w;
        col[0] = c4.x; col[1] = c4.y; col[2] = c4.z; col[3] = c4.w;
    } else {
#pragma unroll
        for (int i = 0; i < 4; ++i) {
            int e = e0 + i;
            if (e < E_RAW) { row[i] = ei[e]; col[i] = ei[E_RAW + e]; }
            else { row[i] = e - E_RAW; col[i] = row[i]; }
        }
    }
    int pos[4];
#pragma unroll
    for (int i = 0; i < 4; ++i)
        pos[i] = (e0 + i < E_TOT) ? atomicAdd(&cur[col[i]], 1) : 0;
#pragma unroll
    for (int i = 0; i < 4; ++i)
        if (e0 + i < E_TOT) srcs[pos[i]] = (unsigned short)row[i];
}

// ---------------- GEMM 1: h1 = x @ W1 (K=128, NC=128), bf16 out + attn1 ----------------
__global__ void k_gemm1(const float* __restrict__ A, const float* __restrict__ B,
                        const float* __restrict__ aux, uint2* __restrict__ C,
                        float* __restrict__ es, float* __restrict__ ed) {
    constexpr int K = 128, MT = 16;
    __shared__ float As[MT * K];   // 8 KB
    int m0 = blockIdx.x * MT;
    int t = threadIdx.x, g = t >> 5, l = t & 31;
    const float4* A4 = (const float4*)(A + (size_t)m0 * K);
    float4* S4 = (float4*)As;
#pragma unroll
    for (int i = 0; i < 8; ++i) S4[t + 64 * i] = A4[t + 64 * i];
    __syncthreads();
    float acc[8][4];
#pragma unroll
    for (int r = 0; r < 8; ++r)
#pragma unroll
        for (int c = 0; c < 4; ++c) acc[r][c] = 0.f;
    const float4* B4 = (const float4*)B;   // row k = 32 float4
    for (int kk = 0; kk < K / 4; ++kk) {
        float4 b0 = B4[(4 * kk + 0) * 32 + l];
        float4 b1 = B4[(4 * kk + 1) * 32 + l];
        float4 b2 = B4[(4 * kk + 2) * 32 + l];
        float4 b3 = B4[(4 * kk + 3) * 32 + l];
#pragma unroll
        for (int r = 0; r < 8; ++r) {
            float4 a = ((const float4*)(As + (g * 8 + r) * K))[kk];
            acc[r][0] = fmaf(a.x, b0.x, fmaf(a.y, b1.x, fmaf(a.z, b2.x, fmaf(a.w, b3.x, acc[r][0]))));
            acc[r][1] = fmaf(a.x, b0.y, fmaf(a.y, b1.y, fmaf(a.z, b2.y, fmaf(a.w, b3.y, acc[r][1]))));
            acc[r][2] = fmaf(a.x, b0.z, fmaf(a.y, b1.z, fmaf(a.z, b2.z, fmaf(a.w, b3.z, acc[r][2]))));
            acc[r][3] = fmaf(a.x, b0.w, fmaf(a.y, b1.w, fmaf(a.z, b2.w, fmaf(a.w, b3.w, acc[r][3]))));
        }
    }
#pragma unroll
    for (int r = 0; r < 8; ++r) {
        int row = m0 + g * 8 + r;
        uint2 v; v.x = pack2(acc[r][0], acc[r][1]); v.y = pack2(acc[r][2], acc[r][3]);
        C[(size_t)row * 32 + l] = v;
    }
    int h = l >> 3, f0 = 4 * (l & 7);
    float al0 = aux[h * 64 + f0], al1 = aux[h * 64 + f0 + 1], al2 = aux[h * 64 + f0 + 2], al3 = aux[h * 64 + f0 + 3];
    float ar0 = aux[h * 64 + 32 + f0], ar1 = aux[h * 64 + 32 + f0 + 1], ar2 = aux[h * 64 + 32 + f0 + 2], ar3 = aux[h * 64 + 32 + f0 + 3];
#pragma unroll
    for (int r = 0; r < 8; ++r) {
        float pl = acc[r][0] * al0 + acc[r][1] * al1 + acc[r][2] * al2 + acc[r][3] * al3;
        float pr = acc[r][0] * ar0 + acc[r][1] * ar1 + acc[r][2] * ar2 + acc[r][3] * ar3;
#pragma unroll
        for (int mask = 4; mask; mask >>= 1) { pl += __shfl_xor(pl, mask); pr += __shfl_xor(pr, mask); }
        if ((l & 7) == 0) {
            int row = m0 + g * 8 + r;
            es[row * 4 + h] = pl; ed[row * 4 + h] = pr;
        }
    }
}

// ---------------- GEMM 2/3: NC=64 ----------------
template<int K, int EPI>
__global__ void k_gemm23(const float* __restrict__ A, const float* __restrict__ B,
                         const float* __restrict__ aux, void* __restrict__ Cv,
                         float* __restrict__ es, float* __restrict__ ed) {
    constexpr int MT = 32;
    __shared__ float As[MT * K];
    int m0 = blockIdx.x * MT;
    int t = threadIdx.x, g = t >> 4, l = t & 15;
    int rows = min(MT, N_NODES - m0);
    const float4* A4 = (const float4*)(A + (size_t)m0 * K);
    float4* S4 = (float4*)As;
    for (int i = t; i < rows * (K / 4); i += 64) S4[i] = A4[i];
    __syncthreads();
    float acc[8][4];
#pragma unroll
    for (int r = 0; r < 8; ++r)
#pragma unroll
        for (int c = 0; c < 4; ++c) acc[r][c] = 0.f;
    const float4* B4 = (const float4*)B;   // row k = 16 float4
    for (int kk = 0; kk < K / 4; ++kk) {
        float4 b0 = B4[(4 * kk + 0) * 16 + l];
        float4 b1 = B4[(4 * kk + 1) * 16 + l];
        float4 b2 = B4[(4 * kk + 2) * 16 + l];
        float4 b3 = B4[(4 * kk + 3) * 16 + l];
#pragma unroll
        for (int r = 0; r < 8; ++r) {
            float4 a = ((const float4*)(As + (g * 8 + r) * K))[kk];
            acc[r][0] = fmaf(a.x, b0.x, fmaf(a.y, b1.x, fmaf(a.z, b2.x, fmaf(a.w, b3.x, acc[r][0]))));
            acc[r][1] = fmaf(a.x, b0.y, fmaf(a.y, b1.y, fmaf(a.z, b2.y, fmaf(a.w, b3.y, acc[r][1]))));
            acc[r][2] = fmaf(a.x, b0.z, fmaf(a.y, b1.z, fmaf(a.z, b2.z, fmaf(a.w, b3.z, acc[r][2]))));
            acc[r][3] = fmaf(a.x, b0.w, fmaf(a.y, b1.w, fmaf(a.z, b2.w, fmaf(a.w, b3.w, acc[r][3]))));
        }
    }
    if (EPI == 2) {
        uint2* C = (uint2*)Cv;
        float al0 = aux[4 * l], al1 = aux[4 * l + 1], al2 = aux[4 * l + 2], al3 = aux[4 * l + 3];
        float ar0 = aux[64 + 4 * l], ar1 = aux[64 + 4 * l + 1], ar2 = aux[64 + 4 * l + 2], ar3 = aux[64 + 4 * l + 3];
#pragma unroll
        for (int r = 0; r < 8; ++r) {
            int row = m0 + g * 8 + r;
            float pl = acc[r][0] * al0 + acc[r][1] * al1 + acc[r][2] * al2 + acc[r][3] * al3;
            float pr = acc[r][0] * ar0 + acc[r][1] * ar1 + acc[r][2] * ar2 + acc[r][3] * ar3;
#pragma unroll
            for (int mask = 8; mask; mask >>= 1) { pl += __shfl_xor(pl, mask); pr += __shfl_xor(pr, mask); }
            if (row < N_NODES) {
                uint2 v; v.x = pack2(acc[r][0], acc[r][1]); v.y = pack2(acc[r][2], acc[r][3]);
                C[(size_t)row * 16 + l] = v;
                if (l == 0) { es[row] = pl; ed[row] = pr; }
            }
        }
    } else {
        float4* C = (float4*)Cv;
        float4 bv = ((const float4*)aux)[l];
#pragma unroll
        for (int r = 0; r < 8; ++r) {
            int row = m0 + g * 8 + r;
            if (row < N_NODES) {
                float4 v;
                v.x = acc[r][0] + bv.x; v.y = acc[r][1] + bv.y;
                v.z = acc[r][2] + bv.z; v.w = acc[r][3] + bv.w;
                C[(size_t)row * 16 + l] = v;
            }
        }
    }
}

// ---------------- layer-1 fused softmax+aggregate: one wave per node ----------------
__global__ void k_agg1(const unsigned* __restrict__ h1b, const float* __restrict__ es,
                       const float* __restrict__ ed, const int* __restrict__ off,
                       const unsigned short* __restrict__ srcs, float* __restrict__ out1) {
    int n = blockIdx.x * (blockDim.x >> 6) + (threadIdx.x >> 6);
    int lane = threadIdx.x & 63;
    if (n >= N_NODES) return;
    int myh = lane & 3;
    float edh = ed[n * 4 + myh];
    int hc = lane >> 4;
    int s = off[n], e = off[n + 1];
    int jj = lane >> 2;
    float ax = 0.f, ay = 0.f, psum = 0.f;
    for (int base = s; base < e; base += 16) {
        int cnt = e - base;
        int srcj = 0;
        float w = 0.f;
        if (jj < cnt) {
            srcj = srcs[base + jj];
            w = __expf(lrelu(es[srcj * 4 + myh] + edh));
        }
        psum += w;
#pragma unroll
        for (int j2 = 0; j2 < 16; ++j2) {
            int src = __shfl(srcj, j2 * 4);
            float wc = __shfl(w, j2 * 4 + hc);
            unsigned p = h1b[(size_t)src * 64 + lane];
            ax = fmaf(bflo(p), wc, ax);
            ay = fmaf(bfhi(p), wc, ay);
        }
    }
#pragma unroll
    for (int mask = 4; mask <= 32; mask <<= 1) psum += __shfl_xor(psum, mask);
    float inv = 1.f / __shfl(psum, hc);
    float2 o;
    o.x = fmaxf(ax * inv, 0.f);
    o.y = fmaxf(ay * inv, 0.f);
    ((float2*)out1)[(size_t)n * 64 + lane] = o;
}

// ---------------- layer-2 fused softmax+aggregate: half-wave per node ----------------
__global__ void k_agg2(const unsigned* __restrict__ h2b, const float* __restrict__ es,
                       const float* __restrict__ ed, const int* __restrict__ off,
                       const unsigned short* __restrict__ srcs, float* __restrict__ outv) {
    int n = blockIdx.x * (blockDim.x >> 5) + (threadIdx.x >> 5);
    int l = threadIdx.x & 31;
    int hb = threadIdx.x & 32;
    if (n >= N_NODES) return;
    float edv = ed[n];
    int s = off[n], e = off[n + 1];
    float ax = 0.f, ay = 0.f, psum = 0.f;
    for (int base = s; base < e; base += 32) {
        int cnt = e - base;
        int srcj = 0;
        float w = 0.f;
        if (l < cnt) {
            srcj = srcs[base + l];
            w = __expf(lrelu(es[srcj] + edv));
        }
        psum += w;
#pragma unroll
        for (int j = 0; j < 32; ++j) {
            int src = __shfl(srcj, hb + j);
            float wj = __shfl(w, hb + j);
            unsigned p = h2b[(size_t)src * 32 + l];
            ax = fmaf(bflo(p), wj, ax);
            ay = fmaf(bfhi(p), wj, ay);
        }
    }
#pragma unroll
    for (int mask = 1; mask <= 16; mask <<= 1) psum += __shfl_xor(psum, mask);
    float inv = 1.f / psum;
    float2 o; o.x = ax * inv; o.y = ay * inv;
    ((float2*)outv)[(size_t)n * 32 + l] = o;
}

extern "C" void kernel_launch(void* const* d_in, const int* in_sizes, int n_in,
                              void* d_out, int out_size, void* d_ws, size_t ws_size,
                              hipStream_t stream) {
    const float* x     = (const float*)d_in[0];
    const int*   ei    = (const int*)d_in[1];
    const float* W1    = (const float*)d_in[2];
    const float* attn1 = (const float*)d_in[3];
    const float* W2    = (const float*)d_in[4];
    const float* attn2 = (const float*)d_in[5];
    const float* headW = (const float*)d_in[6];
    const float* headb = (const float*)d_in[7];
    float* out = (float*)d_out;

    char* ws = (char*)d_ws;
    size_t o = 0;
    auto alloc = [&](size_t bytes) -> void* {
        o = (o + 255) & ~(size_t)255;
        void* p = ws + o;
        o += bytes;
        return p;
    };
    unsigned*       h1b    = (unsigned*)alloc((size_t)N_NODES * 128 * 2);
    float*          out1   = (float*)alloc((size_t)N_NODES * 128 * 4);
    unsigned*       h2b    = (unsigned*)alloc((size_t)N_NODES * 64 * 2);
    float*          h2agg  = (float*)alloc((size_t)N_NODES * 64 * 4);
    float*          e1s    = (float*)alloc((size_t)N_NODES * 4 * 4);
    float*          e1d    = (float*)alloc((size_t)N_NODES * 4 * 4);
    float*          e2s    = (float*)alloc((size_t)N_NODES * 4);
    float*          e2d    = (float*)alloc((size_t)N_NODES * 4);
    int*            deg    = (int*)alloc((size_t)N_NODES * 4);
    int*            off    = (int*)alloc((size_t)(N_NODES + 1) * 4);
    int*            cur    = (int*)alloc((size_t)N_NODES * 4);
    unsigned short* srcs   = (unsigned short*)alloc((size_t)E_TOT * 2);
    int*            blksum = (int*)alloc((size_t)NBLK * 4);
    int*            blkoff = (int*)alloc((size_t)NBLK * 4);

    // CSR build
    (void)hipMemsetAsync(deg, 0, (size_t)N_NODES * 4, stream);
    k_deg<<<(E_TOT / 4 + 255) / 256, 256, 0, stream>>>(ei, deg);
    k_scan1<<<NBLK, 1024, 0, stream>>>(deg, off, blksum);
    k_scan2<<<1, 64, 0, stream>>>(blksum, blkoff, off);
    k_scan3<<<(N_NODES + 255) / 256, 256, 0, stream>>>(off, blkoff, cur);
    k_scatter<<<(E_TOT / 4 + 255) / 256, 256, 0, stream>>>(ei, cur, srcs);

    // layer 1
    k_gemm1<<<N_NODES / 16, 64, 0, stream>>>(x, W1, attn1, (uint2*)h1b, e1s, e1d);
    k_agg1<<<N_NODES / 4, 256, 0, stream>>>(h1b, e1s, e1d, off, srcs, out1);

    // layer 2
    k_gemm23<128, 2><<<(N_NODES + 31) / 32, 64, 0, stream>>>(out1, W2, attn2, h2b, e2s, e2d);
    k_agg2<<<N_NODES / 8, 256, 0, stream>>>(h2b, e2s, e2d, off, srcs, h2agg);

    // head
    k_gemm23<64, 3><<<(N_NODES + 31) / 32, 64, 0, stream>>>(h2agg, headW, headb, out, nullptr, nullptr);
}

// Round 10
// 310.509 us; speedup vs baseline: 1.2309x; 1.0031x over previous
//
#include <hip/hip_runtime.h>
#include <math.h>

#define N_NODES 50000
#define E_RAW 800000
#define E_TOT 850000
#define NEG_SLOPE 0.2f
#define NBLK ((N_NODES + 1023) / 1024)

__device__ __forceinline__ float lrelu(float a) { return a > 0.f ? a : NEG_SLOPE * a; }

__device__ __forceinline__ unsigned f2bf(float f) {
    unsigned u = __float_as_uint(f);
    return (u + 0x7fff + ((u >> 16) & 1)) >> 16;
}
__device__ __forceinline__ unsigned pack2(float a, float b) {
    return f2bf(a) | (f2bf(b) << 16);
}
__device__ __forceinline__ float bflo(unsigned p) { return __uint_as_float(p << 16); }
__device__ __forceinline__ float bfhi(unsigned p) { return __uint_as_float(p & 0xffff0000u); }

// ---------------- CSR build (dst-major), 4 edges/thread for atomic ILP ----------------
__global__ void k_deg(const int* __restrict__ ei, int* __restrict__ deg) {
    int t = blockIdx.x * blockDim.x + threadIdx.x;
    int e0 = 4 * t;
    if (e0 >= E_TOT) return;
    int col[4];
    if (e0 + 3 < E_RAW) {
        int4 c4 = ((const int4*)(ei + E_RAW))[t];
        col[0] = c4.x; col[1] = c4.y; col[2] = c4.z; col[3] = c4.w;
    } else {
#pragma unroll
        for (int i = 0; i < 4; ++i) {
            int e = e0 + i;
            col[i] = (e < E_RAW) ? ei[E_RAW + e] : (e - E_RAW);
        }
    }
#pragma unroll
    for (int i = 0; i < 4; ++i)
        if (e0 + i < E_TOT) atomicAdd(&deg[col[i]], 1);
}

__global__ void k_scan1(const int* __restrict__ deg, int* __restrict__ off, int* __restrict__ blksum) {
    __shared__ int sh[1024];
    int b = blockIdx.x;
    int i = b * 1024 + threadIdx.x;
    int v = (i < N_NODES) ? deg[i] : 0;
    sh[threadIdx.x] = v;
    __syncthreads();
    for (int ofs = 1; ofs < 1024; ofs <<= 1) {
        int t = (threadIdx.x >= ofs) ? sh[threadIdx.x - ofs] : 0;
        __syncthreads();
        sh[threadIdx.x] += t;
        __syncthreads();
    }
    if (i < N_NODES) off[i] = sh[threadIdx.x] - v;
    if (threadIdx.x == 1023) blksum[b] = sh[1023];
}

__global__ void k_scan2(const int* __restrict__ blksum, int* __restrict__ blkoff, int* __restrict__ off) {
    int l = threadIdx.x & 63;
    int v = (l < NBLK) ? blksum[l] : 0;
    int incl = v;
    for (int ofs = 1; ofs < 64; ofs <<= 1) {
        int t = __shfl_up(incl, ofs);
        if (l >= ofs) incl += t;
    }
    if (l < NBLK) blkoff[l] = incl - v;
    if (l == 63) off[N_NODES] = incl;
}

__global__ void k_scan3(int* __restrict__ off, const int* __restrict__ blkoff, int* __restrict__ cur) {
    int i = blockIdx.x * blockDim.x + threadIdx.x;
    if (i >= N_NODES) return;
    int v = off[i] + blkoff[i >> 10];
    off[i] = v;
    cur[i] = v;
}

__global__ void k_scatter(const int* __restrict__ ei, int* __restrict__ cur,
                          unsigned short* __restrict__ srcs) {
    int t = blockIdx.x * blockDim.x + threadIdx.x;
    int e0 = 4 * t;
    if (e0 >= E_TOT) return;
    int row[4], col[4];
    if (e0 + 3 < E_RAW) {
        int4 r4 = ((const int4*)ei)[t];
        int4 c4 = ((const int4*)(ei + E_RAW))[t];
        row[0] = r4.x; row[1] = r4.y; row[2] = r4.z; row[3] = r4.w;
        col[0] = c4.x; col[1] = c4.y; col[2] = c4.z; col[3] = c4.w;
    } else {
#pragma unroll
        for (int i = 0; i < 4; ++i) {
            int e = e0 + i;
            if (e < E_RAW) { row[i] = ei[e]; col[i] = ei[E_RAW + e]; }
            else { row[i] = e - E_RAW; col[i] = row[i]; }
        }
    }
    int pos[4];
#pragma unroll
    for (int i = 0; i < 4; ++i)
        pos[i] = (e0 + i < E_TOT) ? atomicAdd(&cur[col[i]], 1) : 0;
#pragma unroll
    for (int i = 0; i < 4; ++i)
        if (e0 + i < E_TOT) srcs[pos[i]] = (unsigned short)row[i];
}

// ---------------- GEMM 1: h1 = x @ W1 (K=128, NC=128), bf16 out + attn1 ----------------
__global__ void k_gemm1(const float* __restrict__ A, const float* __restrict__ B,
                        const float* __restrict__ aux, uint2* __restrict__ C,
                        float* __restrict__ es, float* __restrict__ ed) {
    constexpr int K = 128, MT = 16;
    __shared__ float As[MT * K];   // 8 KB
    int m0 = blockIdx.x * MT;
    int t = threadIdx.x, g = t >> 5, l = t & 31;
    const float4* A4 = (const float4*)(A + (size_t)m0 * K);
    float4* S4 = (float4*)As;
#pragma unroll
    for (int i = 0; i < 8; ++i) S4[t + 64 * i] = A4[t + 64 * i];
    __syncthreads();
    float acc[8][4];
#pragma unroll
    for (int r = 0; r < 8; ++r)
#pragma unroll
        for (int c = 0; c < 4; ++c) acc[r][c] = 0.f;
    const float4* B4 = (const float4*)B;   // row k = 32 float4
    for (int kk = 0; kk < K / 4; ++kk) {
        float4 b0 = B4[(4 * kk + 0) * 32 + l];
        float4 b1 = B4[(4 * kk + 1) * 32 + l];
        float4 b2 = B4[(4 * kk + 2) * 32 + l];
        float4 b3 = B4[(4 * kk + 3) * 32 + l];
#pragma unroll
        for (int r = 0; r < 8; ++r) {
            float4 a = ((const float4*)(As + (g * 8 + r) * K))[kk];
            acc[r][0] = fmaf(a.x, b0.x, fmaf(a.y, b1.x, fmaf(a.z, b2.x, fmaf(a.w, b3.x, acc[r][0]))));
            acc[r][1] = fmaf(a.x, b0.y, fmaf(a.y, b1.y, fmaf(a.z, b2.y, fmaf(a.w, b3.y, acc[r][1]))));
            acc[r][2] = fmaf(a.x, b0.z, fmaf(a.y, b1.z, fmaf(a.z, b2.z, fmaf(a.w, b3.z, acc[r][2]))));
            acc[r][3] = fmaf(a.x, b0.w, fmaf(a.y, b1.w, fmaf(a.z, b2.w, fmaf(a.w, b3.w, acc[r][3]))));
        }
    }
#pragma unroll
    for (int r = 0; r < 8; ++r) {
        int row = m0 + g * 8 + r;
        uint2 v; v.x = pack2(acc[r][0], acc[r][1]); v.y = pack2(acc[r][2], acc[r][3]);
        C[(size_t)row * 32 + l] = v;
    }
    int h = l >> 3, f0 = 4 * (l & 7);
    float al0 = aux[h * 64 + f0], al1 = aux[h * 64 + f0 + 1], al2 = aux[h * 64 + f0 + 2], al3 = aux[h * 64 + f0 + 3];
    float ar0 = aux[h * 64 + 32 + f0], ar1 = aux[h * 64 + 32 + f0 + 1], ar2 = aux[h * 64 + 32 + f0 + 2], ar3 = aux[h * 64 + 32 + f0 + 3];
#pragma unroll
    for (int r = 0; r < 8; ++r) {
        float pl = acc[r][0] * al0 + acc[r][1] * al1 + acc[r][2] * al2 + acc[r][3] * al3;
        float pr = acc[r][0] * ar0 + acc[r][1] * ar1 + acc[r][2] * ar2 + acc[r][3] * ar3;
#pragma unroll
        for (int mask = 4; mask; mask >>= 1) { pl += __shfl_xor(pl, mask); pr += __shfl_xor(pr, mask); }
        if ((l & 7) == 0) {
            int row = m0 + g * 8 + r;
            es[row * 4 + h] = pl; ed[row * 4 + h] = pr;
        }
    }
}

// ---------------- GEMM 2/3: NC=64 ----------------
template<int K, int EPI>
__global__ void k_gemm23(const float* __restrict__ A, const float* __restrict__ B,
                         const float* __restrict__ aux, void* __restrict__ Cv,
                         float* __restrict__ es, float* __restrict__ ed) {
    constexpr int MT = 32;
    __shared__ float As[MT * K];
    int m0 = blockIdx.x * MT;
    int t = threadIdx.x, g = t >> 4, l = t & 15;
    int rows = min(MT, N_NODES - m0);
    const float4* A4 = (const float4*)(A + (size_t)m0 * K);
    float4* S4 = (float4*)As;
    for (int i = t; i < rows * (K / 4); i += 64) S4[i] = A4[i];
    __syncthreads();
    float acc[8][4];
#pragma unroll
    for (int r = 0; r < 8; ++r)
#pragma unroll
        for (int c = 0; c < 4; ++c) acc[r][c] = 0.f;
    const float4* B4 = (const float4*)B;   // row k = 16 float4
    for (int kk = 0; kk < K / 4; ++kk) {
        float4 b0 = B4[(4 * kk + 0) * 16 + l];
        float4 b1 = B4[(4 * kk + 1) * 16 + l];
        float4 b2 = B4[(4 * kk + 2) * 16 + l];
        float4 b3 = B4[(4 * kk + 3) * 16 + l];
#pragma unroll
        for (int r = 0; r < 8; ++r) {
            float4 a = ((const float4*)(As + (g * 8 + r) * K))[kk];
            acc[r][0] = fmaf(a.x, b0.x, fmaf(a.y, b1.x, fmaf(a.z, b2.x, fmaf(a.w, b3.x, acc[r][0]))));
            acc[r][1] = fmaf(a.x, b0.y, fmaf(a.y, b1.y, fmaf(a.z, b2.y, fmaf(a.w, b3.y, acc[r][1]))));
            acc[r][2] = fmaf(a.x, b0.z, fmaf(a.y, b1.z, fmaf(a.z, b2.z, fmaf(a.w, b3.z, acc[r][2]))));
            acc[r][3] = fmaf(a.x, b0.w, fmaf(a.y, b1.w, fmaf(a.z, b2.w, fmaf(a.w, b3.w, acc[r][3]))));
        }
    }
    if (EPI == 2) {
        uint2* C = (uint2*)Cv;
        float al0 = aux[4 * l], al1 = aux[4 * l + 1], al2 = aux[4 * l + 2], al3 = aux[4 * l + 3];
        float ar0 = aux[64 + 4 * l], ar1 = aux[64 + 4 * l + 1], ar2 = aux[64 + 4 * l + 2], ar3 = aux[64 + 4 * l + 3];
#pragma unroll
        for (int r = 0; r < 8; ++r) {
            int row = m0 + g * 8 + r;
            float pl = acc[r][0] * al0 + acc[r][1] * al1 + acc[r][2] * al2 + acc[r][3] * al3;
            float pr = acc[r][0] * ar0 + acc[r][1] * ar1 + acc[r][2] * ar2 + acc[r][3] * ar3;
#pragma unroll
            for (int mask = 8; mask; mask >>= 1) { pl += __shfl_xor(pl, mask); pr += __shfl_xor(pr, mask); }
            if (row < N_NODES) {
                uint2 v; v.x = pack2(acc[r][0], acc[r][1]); v.y = pack2(acc[r][2], acc[r][3]);
                C[(size_t)row * 16 + l] = v;
                if (l == 0) { es[row] = pl; ed[row] = pr; }
            }
        }
    } else {
        float4* C = (float4*)Cv;
        float4 bv = ((const float4*)aux)[l];
#pragma unroll
        for (int r = 0; r < 8; ++r) {
            int row = m0 + g * 8 + r;
            if (row < N_NODES) {
                float4 v;
                v.x = acc[r][0] + bv.x; v.y = acc[r][1] + bv.y;
                v.z = acc[r][2] + bv.z; v.w = acc[r][3] + bv.w;
                C[(size_t)row * 16 + l] = v;
            }
        }
    }
}

// ---------------- layer-1 fused softmax+aggregate: one wave per node ----------------
// Two-phase chunks: batch-issue 16 independent gathers into registers, then FMA.
__global__ void k_agg1(const unsigned* __restrict__ h1b, const float* __restrict__ es,
                       const float* __restrict__ ed, const int* __restrict__ off,
                       const unsigned short* __restrict__ srcs, float* __restrict__ out1) {
    int n = blockIdx.x * (blockDim.x >> 6) + (threadIdx.x >> 6);
    int lane = threadIdx.x & 63;
    if (n >= N_NODES) return;
    int myh = lane & 3;
    float edh = ed[n * 4 + myh];
    int hc = lane >> 4;
    int s = off[n], e = off[n + 1];
    int jj = lane >> 2;
    float ax = 0.f, ay = 0.f, psum = 0.f;
    for (int base = s; base < e; base += 16) {
        int cnt = e - base;
        int srcj = 0;
        float w = 0.f;
        if (jj < cnt) {
            srcj = srcs[base + jj];
            w = __expf(lrelu(es[srcj * 4 + myh] + edh));
        }
        psum += w;
        unsigned pv[16];
        float wv[16];
        // phase 1: broadcast src + issue all 16 gathers (independent, pipelined)
#pragma unroll
        for (int j2 = 0; j2 < 16; ++j2) {
            int src = __shfl(srcj, j2 * 4);
            wv[j2] = __shfl(w, j2 * 4 + hc);
            pv[j2] = h1b[(size_t)src * 64 + lane];
        }
        // phase 2: consume
#pragma unroll
        for (int j2 = 0; j2 < 16; ++j2) {
            ax = fmaf(bflo(pv[j2]), wv[j2], ax);
            ay = fmaf(bfhi(pv[j2]), wv[j2], ay);
        }
    }
#pragma unroll
    for (int mask = 4; mask <= 32; mask <<= 1) psum += __shfl_xor(psum, mask);
    float inv = 1.f / __shfl(psum, hc);
    float2 o;
    o.x = fmaxf(ax * inv, 0.f);
    o.y = fmaxf(ay * inv, 0.f);
    ((float2*)out1)[(size_t)n * 64 + lane] = o;
}

// ---------------- layer-2 fused softmax+aggregate: half-wave per node ----------------
// 32-edge chunks. Lane group l<16 handles edges 0..15, group l>=16 handles 16..31
// (disjoint!), each lane gathering uint2 = feats 4*l16..4*l16+3; groups merged at end.
__global__ void k_agg2(const unsigned* __restrict__ h2b, const float* __restrict__ es,
                       const float* __restrict__ ed, const int* __restrict__ off,
                       const unsigned short* __restrict__ srcs, float* __restrict__ outv) {
    int n = blockIdx.x * (blockDim.x >> 5) + (threadIdx.x >> 5);
    int l = threadIdx.x & 31;
    int hb = threadIdx.x & 32;   // base lane of my half within the wave
    if (n >= N_NODES) return;
    float edv = ed[n];
    int s = off[n], e = off[n + 1];
    const uint2* gp = (const uint2*)h2b;   // row = 16 uint2
    int l16 = l & 15;
    int sb0 = (l >> 4) * 2;   // group 0 -> subs 0,1 ; group 1 -> subs 2,3
    float a0 = 0.f, a1 = 0.f, a2 = 0.f, a3 = 0.f, psum = 0.f;
    for (int base = s; base < e; base += 32) {
        int cnt = e - base;
        int srcj = 0;
        float w = 0.f;
        if (l < cnt) {
            srcj = srcs[base + l];
            w = __expf(lrelu(es[srcj] + edv));
        }
        psum += w;
#pragma unroll
        for (int sub = 0; sub < 2; ++sub) {
            uint2 pv[8];
            float wv[8];
#pragma unroll
            for (int j = 0; j < 8; ++j) {
                int lsrc = hb + (sb0 + sub) * 8 + j;
                int src = __shfl(srcj, lsrc);
                wv[j] = __shfl(w, lsrc);
                pv[j] = gp[(size_t)src * 16 + l16];
            }
#pragma unroll
            for (int j = 0; j < 8; ++j) {
                a0 = fmaf(bflo(pv[j].x), wv[j], a0);
                a1 = fmaf(bfhi(pv[j].x), wv[j], a1);
                a2 = fmaf(bflo(pv[j].y), wv[j], a2);
                a3 = fmaf(bfhi(pv[j].y), wv[j], a3);
            }
        }
    }
#pragma unroll
    for (int mask = 1; mask <= 16; mask <<= 1) psum += __shfl_xor(psum, mask);
    float inv = 1.f / psum;
    // merge the two disjoint edge-range accumulators (lane pairs l, l^16)
    a0 += __shfl_xor(a0, 16); a1 += __shfl_xor(a1, 16);
    a2 += __shfl_xor(a2, 16); a3 += __shfl_xor(a3, 16);
    if (l < 16) {
        float4 o;
        o.x = a0 * inv; o.y = a1 * inv; o.z = a2 * inv; o.w = a3 * inv;
        ((float4*)outv)[(size_t)n * 16 + l16] = o;
    }
}

extern "C" void kernel_launch(void* const* d_in, const int* in_sizes, int n_in,
                              void* d_out, int out_size, void* d_ws, size_t ws_size,
                              hipStream_t stream) {
    const float* x     = (const float*)d_in[0];
    const int*   ei    = (const int*)d_in[1];
    const float* W1    = (const float*)d_in[2];
    const float* attn1 = (const float*)d_in[3];
    const float* W2    = (const float*)d_in[4];
    const float* attn2 = (const float*)d_in[5];
    const float* headW = (const float*)d_in[6];
    const float* headb = (const float*)d_in[7];
    float* out = (float*)d_out;

    char* ws = (char*)d_ws;
    size_t o = 0;
    auto alloc = [&](size_t bytes) -> void* {
        o = (o + 255) & ~(size_t)255;
        void* p = ws + o;
        o += bytes;
        return p;
    };
    unsigned*       h1b    = (unsigned*)alloc((size_t)N_NODES * 128 * 2);
    float*          out1   = (float*)alloc((size_t)N_NODES * 128 * 4);
    unsigned*       h2b    = (unsigned*)alloc((size_t)N_NODES * 64 * 2);
    float*          h2agg  = (float*)alloc((size_t)N_NODES * 64 * 4);
    float*          e1s    = (float*)alloc((size_t)N_NODES * 4 * 4);
    float*          e1d    = (float*)alloc((size_t)N_NODES * 4 * 4);
    float*          e2s    = (float*)alloc((size_t)N_NODES * 4);
    float*          e2d    = (float*)alloc((size_t)N_NODES * 4);
    int*            deg    = (int*)alloc((size_t)N_NODES * 4);
    int*            off    = (int*)alloc((size_t)(N_NODES + 1) * 4);
    int*            cur    = (int*)alloc((size_t)N_NODES * 4);
    unsigned short* srcs   = (unsigned short*)alloc((size_t)E_TOT * 2);
    int*            blksum = (int*)alloc((size_t)NBLK * 4);
    int*            blkoff = (int*)alloc((size_t)NBLK * 4);

    // CSR build
    (void)hipMemsetAsync(deg, 0, (size_t)N_NODES * 4, stream);
    k_deg<<<(E_TOT / 4 + 255) / 256, 256, 0, stream>>>(ei, deg);
    k_scan1<<<NBLK, 1024, 0, stream>>>(deg, off, blksum);
    k_scan2<<<1, 64, 0, stream>>>(blksum, blkoff, off);
    k_scan3<<<(N_NODES + 255) / 256, 256, 0, stream>>>(off, blkoff, cur);
    k_scatter<<<(E_TOT / 4 + 255) / 256, 256, 0, stream>>>(ei, cur, srcs);

    // layer 1
    k_gemm1<<<N_NODES / 16, 64, 0, stream>>>(x, W1, attn1, (uint2*)h1b, e1s, e1d);
    k_agg1<<<N_NODES / 4, 256, 0, stream>>>(h1b, e1s, e1d, off, srcs, out1);

    // layer 2
    k_gemm23<128, 2><<<(N_NODES + 31) / 32, 64, 0, stream>>>(out1, W2, attn2, h2b, e2s, e2d);
    k_agg2<<<N_NODES / 8, 256, 0, stream>>>(h2b, e2s, e2d, off, srcs, h2agg);

    // head
    k_gemm23<64, 3><<<(N_NODES + 31) / 32, 64, 0, stream>>>(h2agg, headW, headb, out, nullptr, nullptr);
}

// Round 11
// 285.061 us; speedup vs baseline: 1.3408x; 1.0893x over previous
//
#include <hip/hip_runtime.h>
#include <math.h>

#define N_NODES 50000
#define E_RAW 800000
#define E_TOT 850000
#define NEG_SLOPE 0.2f
#define NBLK ((N_NODES + 1023) / 1024)

__device__ __forceinline__ float lrelu(float a) { return a > 0.f ? a : NEG_SLOPE * a; }

__device__ __forceinline__ unsigned f2bf(float f) {
    unsigned u = __float_as_uint(f);
    return (u + 0x7fff + ((u >> 16) & 1)) >> 16;
}
__device__ __forceinline__ unsigned pack2(float a, float b) {
    return f2bf(a) | (f2bf(b) << 16);
}
__device__ __forceinline__ float bflo(unsigned p) { return __uint_as_float(p << 16); }
__device__ __forceinline__ float bfhi(unsigned p) { return __uint_as_float(p & 0xffff0000u); }

// ---------------- CSR build: rank-recording degree pass (atomic-with-return) ----------------
__global__ void k_deg_rank(const int* __restrict__ ei, int* __restrict__ deg,
                           unsigned short* __restrict__ rank) {
    int t = blockIdx.x * blockDim.x + threadIdx.x;
    int e0 = 4 * t;
    if (e0 >= E_TOT) return;
    int col[4];
    if (e0 + 3 < E_RAW) {
        int4 c4 = ((const int4*)(ei + E_RAW))[t];
        col[0] = c4.x; col[1] = c4.y; col[2] = c4.z; col[3] = c4.w;
    } else {
#pragma unroll
        for (int i = 0; i < 4; ++i) {
            int e = e0 + i;
            col[i] = (e < E_RAW) ? ei[E_RAW + e] : (e - E_RAW);
        }
    }
    unsigned short rk[4];
#pragma unroll
    for (int i = 0; i < 4; ++i)
        rk[i] = (e0 + i < E_TOT) ? (unsigned short)atomicAdd(&deg[col[i]], 1) : (unsigned short)0;
    if (e0 + 3 < E_TOT) {
        ushort4 v; v.x = rk[0]; v.y = rk[1]; v.z = rk[2]; v.w = rk[3];
        ((ushort4*)rank)[t] = v;
    } else {
#pragma unroll
        for (int i = 0; i < 4; ++i)
            if (e0 + i < E_TOT) rank[e0 + i] = rk[i];
    }
}

__global__ void k_scan1(const int* __restrict__ deg, int* __restrict__ off, int* __restrict__ blksum) {
    __shared__ int sh[1024];
    int b = blockIdx.x;
    int i = b * 1024 + threadIdx.x;
    int v = (i < N_NODES) ? deg[i] : 0;
    sh[threadIdx.x] = v;
    __syncthreads();
    for (int ofs = 1; ofs < 1024; ofs <<= 1) {
        int t = (threadIdx.x >= ofs) ? sh[threadIdx.x - ofs] : 0;
        __syncthreads();
        sh[threadIdx.x] += t;
        __syncthreads();
    }
    if (i < N_NODES) off[i] = sh[threadIdx.x] - v;
    if (threadIdx.x == 1023) blksum[b] = sh[1023];
}

__global__ void k_scan2(const int* __restrict__ blksum, int* __restrict__ blkoff, int* __restrict__ off) {
    int l = threadIdx.x & 63;
    int v = (l < NBLK) ? blksum[l] : 0;
    int incl = v;
    for (int ofs = 1; ofs < 64; ofs <<= 1) {
        int t = __shfl_up(incl, ofs);
        if (l >= ofs) incl += t;
    }
    if (l < NBLK) blkoff[l] = incl - v;
    if (l == 63) off[N_NODES] = incl;
}

__global__ void k_scan3(int* __restrict__ off, const int* __restrict__ blkoff) {
    int i = blockIdx.x * blockDim.x + threadIdx.x;
    if (i >= N_NODES) return;
    off[i] += blkoff[i >> 10];
}

// atomic-free scatter: position = off[col] + rank[e]
__global__ void k_scatter2(const int* __restrict__ ei, const int* __restrict__ off,
                           const unsigned short* __restrict__ rank,
                           unsigned short* __restrict__ srcs) {
    int t = blockIdx.x * blockDim.x + threadIdx.x;
    int e0 = 4 * t;
    if (e0 >= E_TOT) return;
    int row[4], col[4], rk[4];
    if (e0 + 3 < E_TOT && e0 + 3 < E_RAW) {
        int4 r4 = ((const int4*)ei)[t];
        int4 c4 = ((const int4*)(ei + E_RAW))[t];
        ushort4 k4 = ((const ushort4*)rank)[t];
        row[0] = r4.x; row[1] = r4.y; row[2] = r4.z; row[3] = r4.w;
        col[0] = c4.x; col[1] = c4.y; col[2] = c4.z; col[3] = c4.w;
        rk[0] = k4.x; rk[1] = k4.y; rk[2] = k4.z; rk[3] = k4.w;
    } else {
#pragma unroll
        for (int i = 0; i < 4; ++i) {
            int e = e0 + i;
            if (e < E_RAW) { row[i] = ei[e]; col[i] = ei[E_RAW + e]; }
            else { row[i] = e - E_RAW; col[i] = row[i]; }
            rk[i] = (e < E_TOT) ? rank[e] : 0;
        }
    }
#pragma unroll
    for (int i = 0; i < 4; ++i)
        if (e0 + i < E_TOT) srcs[off[col[i]] + rk[i]] = (unsigned short)row[i];
}

// ---------------- GEMM 1: h1 = x @ W1 (K=128, NC=128), bf16 out + attn1 ----------------
// block 128 = 4 row-groups(8 rows) x 32 lanes; MT=32 rows; 4 cols/thread.
// B loads register-prefetched one kk ahead to cover L2 latency with the FMA body.
__global__ void k_gemm1(const float* __restrict__ A, const float* __restrict__ B,
                        const float* __restrict__ aux, uint2* __restrict__ C,
                        float* __restrict__ es, float* __restrict__ ed) {
    constexpr int K = 128, MT = 32;
    __shared__ float As[MT * K];   // 16 KB
    int m0 = blockIdx.x * MT;
    int t = threadIdx.x, g = t >> 5, l = t & 31;
    int rows = min(MT, N_NODES - m0);
    const float4* A4 = (const float4*)(A + (size_t)m0 * K);
    float4* S4 = (float4*)As;
    for (int i = t; i < rows * (K / 4); i += 128) S4[i] = A4[i];
    __syncthreads();
    float acc[8][4];
#pragma unroll
    for (int r = 0; r < 8; ++r)
#pragma unroll
        for (int c = 0; c < 4; ++c) acc[r][c] = 0.f;
    const float4* B4 = (const float4*)B;   // row k = 32 float4
    float4 b0 = B4[0 * 32 + l], b1 = B4[1 * 32 + l], b2 = B4[2 * 32 + l], b3 = B4[3 * 32 + l];
    for (int kk = 0; kk < K / 4 - 1; ++kk) {
        float4 c0 = B4[(4 * kk + 4) * 32 + l];
        float4 c1 = B4[(4 * kk + 5) * 32 + l];
        float4 c2 = B4[(4 * kk + 6) * 32 + l];
        float4 c3 = B4[(4 * kk + 7) * 32 + l];
#pragma unroll
        for (int r = 0; r < 8; ++r) {
            float4 a = ((const float4*)(As + (g * 8 + r) * K))[kk];
            acc[r][0] = fmaf(a.x, b0.x, fmaf(a.y, b1.x, fmaf(a.z, b2.x, fmaf(a.w, b3.x, acc[r][0]))));
            acc[r][1] = fmaf(a.x, b0.y, fmaf(a.y, b1.y, fmaf(a.z, b2.y, fmaf(a.w, b3.y, acc[r][1]))));
            acc[r][2] = fmaf(a.x, b0.z, fmaf(a.y, b1.z, fmaf(a.z, b2.z, fmaf(a.w, b3.z, acc[r][2]))));
            acc[r][3] = fmaf(a.x, b0.w, fmaf(a.y, b1.w, fmaf(a.z, b2.w, fmaf(a.w, b3.w, acc[r][3]))));
        }
        b0 = c0; b1 = c1; b2 = c2; b3 = c3;
    }
    {
        int kk = K / 4 - 1;
#pragma unroll
        for (int r = 0; r < 8; ++r) {
            float4 a = ((const float4*)(As + (g * 8 + r) * K))[kk];
            acc[r][0] = fmaf(a.x, b0.x, fmaf(a.y, b1.x, fmaf(a.z, b2.x, fmaf(a.w, b3.x, acc[r][0]))));
            acc[r][1] = fmaf(a.x, b0.y, fmaf(a.y, b1.y, fmaf(a.z, b2.y, fmaf(a.w, b3.y, acc[r][1]))));
            acc[r][2] = fmaf(a.x, b0.z, fmaf(a.y, b1.z, fmaf(a.z, b2.z, fmaf(a.w, b3.z, acc[r][2]))));
            acc[r][3] = fmaf(a.x, b0.w, fmaf(a.y, b1.w, fmaf(a.z, b2.w, fmaf(a.w, b3.w, acc[r][3]))));
        }
    }
#pragma unroll
    for (int r = 0; r < 8; ++r) {
        int row = m0 + g * 8 + r;
        if (row < N_NODES) {
            uint2 v; v.x = pack2(acc[r][0], acc[r][1]); v.y = pack2(acc[r][2], acc[r][3]);
            C[(size_t)row * 32 + l] = v;
        }
    }
    int h = l >> 3, f0 = 4 * (l & 7);
    float al0 = aux[h * 64 + f0], al1 = aux[h * 64 + f0 + 1], al2 = aux[h * 64 + f0 + 2], al3 = aux[h * 64 + f0 + 3];
    float ar0 = aux[h * 64 + 32 + f0], ar1 = aux[h * 64 + 32 + f0 + 1], ar2 = aux[h * 64 + 32 + f0 + 2], ar3 = aux[h * 64 + 32 + f0 + 3];
#pragma unroll
    for (int r = 0; r < 8; ++r) {
        float pl = acc[r][0] * al0 + acc[r][1] * al1 + acc[r][2] * al2 + acc[r][3] * al3;
        float pr = acc[r][0] * ar0 + acc[r][1] * ar1 + acc[r][2] * ar2 + acc[r][3] * ar3;
#pragma unroll
        for (int mask = 4; mask; mask >>= 1) { pl += __shfl_xor(pl, mask); pr += __shfl_xor(pr, mask); }
        if ((l & 7) == 0) {
            int row = m0 + g * 8 + r;
            if (row < N_NODES) { es[row * 4 + h] = pl; ed[row * 4 + h] = pr; }
        }
    }
}

// ---------------- GEMM 2/3: NC=64 ----------------
template<int K, int EPI>
__global__ void k_gemm23(const float* __restrict__ A, const float* __restrict__ B,
                         const float* __restrict__ aux, void* __restrict__ Cv,
                         float* __restrict__ es, float* __restrict__ ed) {
    constexpr int MT = 32;
    __shared__ float As[MT * K];
    int m0 = blockIdx.x * MT;
    int t = threadIdx.x, g = t >> 4, l = t & 15;
    int rows = min(MT, N_NODES - m0);
    const float4* A4 = (const float4*)(A + (size_t)m0 * K);
    float4* S4 = (float4*)As;
    for (int i = t; i < rows * (K / 4); i += 64) S4[i] = A4[i];
    __syncthreads();
    float acc[8][4];
#pragma unroll
    for (int r = 0; r < 8; ++r)
#pragma unroll
        for (int c = 0; c < 4; ++c) acc[r][c] = 0.f;
    const float4* B4 = (const float4*)B;   // row k = 16 float4
    for (int kk = 0; kk < K / 4; ++kk) {
        float4 b0 = B4[(4 * kk + 0) * 16 + l];
        float4 b1 = B4[(4 * kk + 1) * 16 + l];
        float4 b2 = B4[(4 * kk + 2) * 16 + l];
        float4 b3 = B4[(4 * kk + 3) * 16 + l];
#pragma unroll
        for (int r = 0; r < 8; ++r) {
            float4 a = ((const float4*)(As + (g * 8 + r) * K))[kk];
            acc[r][0] = fmaf(a.x, b0.x, fmaf(a.y, b1.x, fmaf(a.z, b2.x, fmaf(a.w, b3.x, acc[r][0]))));
            acc[r][1] = fmaf(a.x, b0.y, fmaf(a.y, b1.y, fmaf(a.z, b2.y, fmaf(a.w, b3.y, acc[r][1]))));
            acc[r][2] = fmaf(a.x, b0.z, fmaf(a.y, b1.z, fmaf(a.z, b2.z, fmaf(a.w, b3.z, acc[r][2]))));
            acc[r][3] = fmaf(a.x, b0.w, fmaf(a.y, b1.w, fmaf(a.z, b2.w, fmaf(a.w, b3.w, acc[r][3]))));
        }
    }
    if (EPI == 2) {
        uint2* C = (uint2*)Cv;
        float al0 = aux[4 * l], al1 = aux[4 * l + 1], al2 = aux[4 * l + 2], al3 = aux[4 * l + 3];
        float ar0 = aux[64 + 4 * l], ar1 = aux[64 + 4 * l + 1], ar2 = aux[64 + 4 * l + 2], ar3 = aux[64 + 4 * l + 3];
#pragma unroll
        for (int r = 0; r < 8; ++r) {
            int row = m0 + g * 8 + r;
            float pl = acc[r][0] * al0 + acc[r][1] * al1 + acc[r][2] * al2 + acc[r][3] * al3;
            float pr = acc[r][0] * ar0 + acc[r][1] * ar1 + acc[r][2] * ar2 + acc[r][3] * ar3;
#pragma unroll
            for (int mask = 8; mask; mask >>= 1) { pl += __shfl_xor(pl, mask); pr += __shfl_xor(pr, mask); }
            if (row < N_NODES) {
                uint2 v; v.x = pack2(acc[r][0], acc[r][1]); v.y = pack2(acc[r][2], acc[r][3]);
                C[(size_t)row * 16 + l] = v;
                if (l == 0) { es[row] = pl; ed[row] = pr; }
            }
        }
    } else {
        float4* C = (float4*)Cv;
        float4 bv = ((const float4*)aux)[l];
#pragma unroll
        for (int r = 0; r < 8; ++r) {
            int row = m0 + g * 8 + r;
            if (row < N_NODES) {
                float4 v;
                v.x = acc[r][0] + bv.x; v.y = acc[r][1] + bv.y;
                v.z = acc[r][2] + bv.z; v.w = acc[r][3] + bv.w;
                C[(size_t)row * 16 + l] = v;
            }
        }
    }
}

// ---------------- layer-1 fused softmax+aggregate: one wave per node ----------------
__global__ void k_agg1(const unsigned* __restrict__ h1b, const float* __restrict__ es,
                       const float* __restrict__ ed, const int* __restrict__ off,
                       const unsigned short* __restrict__ srcs, float* __restrict__ out1) {
    int n = blockIdx.x * (blockDim.x >> 6) + (threadIdx.x >> 6);
    int lane = threadIdx.x & 63;
    if (n >= N_NODES) return;
    int myh = lane & 3;
    float edh = ed[n * 4 + myh];
    int hc = lane >> 4;
    int s = off[n], e = off[n + 1];
    int jj = lane >> 2;
    float ax = 0.f, ay = 0.f, psum = 0.f;
    for (int base = s; base < e; base += 16) {
        int cnt = e - base;
        int srcj = 0;
        float w = 0.f;
        if (jj < cnt) {
            srcj = srcs[base + jj];
            w = __expf(lrelu(es[srcj * 4 + myh] + edh));
        }
        psum += w;
        unsigned pv[16];
        float wv[16];
#pragma unroll
        for (int j2 = 0; j2 < 16; ++j2) {
            int src = __shfl(srcj, j2 * 4);
            wv[j2] = __shfl(w, j2 * 4 + hc);
            pv[j2] = h1b[(size_t)src * 64 + lane];
        }
#pragma unroll
        for (int j2 = 0; j2 < 16; ++j2) {
            ax = fmaf(bflo(pv[j2]), wv[j2], ax);
            ay = fmaf(bfhi(pv[j2]), wv[j2], ay);
        }
    }
#pragma unroll
    for (int mask = 4; mask <= 32; mask <<= 1) psum += __shfl_xor(psum, mask);
    float inv = 1.f / __shfl(psum, hc);
    float2 o;
    o.x = fmaxf(ax * inv, 0.f);
    o.y = fmaxf(ay * inv, 0.f);
    ((float2*)out1)[(size_t)n * 64 + lane] = o;
}

// ---------------- layer-2 fused softmax+aggregate: half-wave per node ----------------
__global__ void k_agg2(const unsigned* __restrict__ h2b, const float* __restrict__ es,
                       const float* __restrict__ ed, const int* __restrict__ off,
                       const unsigned short* __restrict__ srcs, float* __restrict__ outv) {
    int n = blockIdx.x * (blockDim.x >> 5) + (threadIdx.x >> 5);
    int l = threadIdx.x & 31;
    int hb = threadIdx.x & 32;
    if (n >= N_NODES) return;
    float edv = ed[n];
    int s = off[n], e = off[n + 1];
    const uint2* gp = (const uint2*)h2b;
    int l16 = l & 15;
    int sb0 = (l >> 4) * 2;
    float a0 = 0.f, a1 = 0.f, a2 = 0.f, a3 = 0.f, psum = 0.f;
    for (int base = s; base < e; base += 32) {
        int cnt = e - base;
        int srcj = 0;
        float w = 0.f;
        if (l < cnt) {
            srcj = srcs[base + l];
            w = __expf(lrelu(es[srcj] + edv));
        }
        psum += w;
#pragma unroll
        for (int sub = 0; sub < 2; ++sub) {
            uint2 pv[8];
            float wv[8];
#pragma unroll
            for (int j = 0; j < 8; ++j) {
                int lsrc = hb + (sb0 + sub) * 8 + j;
                int src = __shfl(srcj, lsrc);
                wv[j] = __shfl(w, lsrc);
                pv[j] = gp[(size_t)src * 16 + l16];
            }
#pragma unroll
            for (int j = 0; j < 8; ++j) {
                a0 = fmaf(bflo(pv[j].x), wv[j], a0);
                a1 = fmaf(bfhi(pv[j].x), wv[j], a1);
                a2 = fmaf(bflo(pv[j].y), wv[j], a2);
                a3 = fmaf(bfhi(pv[j].y), wv[j], a3);
            }
        }
    }
#pragma unroll
    for (int mask = 1; mask <= 16; mask <<= 1) psum += __shfl_xor(psum, mask);
    float inv = 1.f / psum;
    a0 += __shfl_xor(a0, 16); a1 += __shfl_xor(a1, 16);
    a2 += __shfl_xor(a2, 16); a3 += __shfl_xor(a3, 16);
    if (l < 16) {
        float4 o;
        o.x = a0 * inv; o.y = a1 * inv; o.z = a2 * inv; o.w = a3 * inv;
        ((float4*)outv)[(size_t)n * 16 + l16] = o;
    }
}

extern "C" void kernel_launch(void* const* d_in, const int* in_sizes, int n_in,
                              void* d_out, int out_size, void* d_ws, size_t ws_size,
                              hipStream_t stream) {
    const float* x     = (const float*)d_in[0];
    const int*   ei    = (const int*)d_in[1];
    const float* W1    = (const float*)d_in[2];
    const float* attn1 = (const float*)d_in[3];
    const float* W2    = (const float*)d_in[4];
    const float* attn2 = (const float*)d_in[5];
    const float* headW = (const float*)d_in[6];
    const float* headb = (const float*)d_in[7];
    float* out = (float*)d_out;

    char* ws = (char*)d_ws;
    size_t o = 0;
    auto alloc = [&](size_t bytes) -> void* {
        o = (o + 255) & ~(size_t)255;
        void* p = ws + o;
        o += bytes;
        return p;
    };
    unsigned*       h1b    = (unsigned*)alloc((size_t)N_NODES * 128 * 2);
    float*          out1   = (float*)alloc((size_t)N_NODES * 128 * 4);
    unsigned*       h2b    = (unsigned*)alloc((size_t)N_NODES * 64 * 2);
    float*          h2agg  = (float*)alloc((size_t)N_NODES * 64 * 4);
    float*          e1s    = (float*)alloc((size_t)N_NODES * 4 * 4);
    float*          e1d    = (float*)alloc((size_t)N_NODES * 4 * 4);
    float*          e2s    = (float*)alloc((size_t)N_NODES * 4);
    float*          e2d    = (float*)alloc((size_t)N_NODES * 4);
    int*            deg    = (int*)alloc((size_t)N_NODES * 4);
    int*            off    = (int*)alloc((size_t)(N_NODES + 1) * 4);
    unsigned short* rank   = (unsigned short*)alloc((size_t)E_TOT * 2);
    unsigned short* srcs   = (unsigned short*)alloc((size_t)E_TOT * 2);
    int*            blksum = (int*)alloc((size_t)NBLK * 4);
    int*            blkoff = (int*)alloc((size_t)NBLK * 4);

    // CSR build (rank-based, scatter is atomic-free)
    (void)hipMemsetAsync(deg, 0, (size_t)N_NODES * 4, stream);
    k_deg_rank<<<(E_TOT / 4 + 255) / 256, 256, 0, stream>>>(ei, deg, rank);
    k_scan1<<<NBLK, 1024, 0, stream>>>(deg, off, blksum);
    k_scan2<<<1, 64, 0, stream>>>(blksum, blkoff, off);
    k_scan3<<<(N_NODES + 255) / 256, 256, 0, stream>>>(off, blkoff);
    k_scatter2<<<(E_TOT / 4 + 255) / 256, 256, 0, stream>>>(ei, off, rank, srcs);

    // layer 1
    k_gemm1<<<(N_NODES + 31) / 32, 128, 0, stream>>>(x, W1, attn1, (uint2*)h1b, e1s, e1d);
    k_agg1<<<N_NODES / 4, 256, 0, stream>>>(h1b, e1s, e1d, off, srcs, out1);

    // layer 2
    k_gemm23<128, 2><<<(N_NODES + 31) / 32, 64, 0, stream>>>(out1, W2, attn2, h2b, e2s, e2d);
    k_agg2<<<N_NODES / 8, 256, 0, stream>>>(h2b, e2s, e2d, off, srcs, h2agg);

    // head
    k_gemm23<64, 3><<<(N_NODES + 31) / 32, 64, 0, stream>>>(h2agg, headW, headb, out, nullptr, nullptr);
}

// Round 12
// 270.106 us; speedup vs baseline: 1.4151x; 1.0554x over previous
//
#include <hip/hip_runtime.h>
#include <math.h>

#define N_NODES 50000
#define E_RAW 800000
#define E_TOT 850000
#define NEG_SLOPE 0.2f
#define NBLK ((N_NODES + 1023) / 1024)
#define G1_BLOCKS ((N_NODES + 31) / 32)          // gemm1 part: MT=32, 128 thr
#define G2_BLOCKS ((E_TOT / 4 + 255) / 256)      // deg_rank part: 256 thr, 4 edges/thr

__device__ __forceinline__ float lrelu(float a) { return a > 0.f ? a : NEG_SLOPE * a; }

__device__ __forceinline__ unsigned f2bf(float f) {
    unsigned u = __float_as_uint(f);
    return (u + 0x7fff + ((u >> 16) & 1)) >> 16;
}
__device__ __forceinline__ unsigned pack2(float a, float b) {
    return f2bf(a) | (f2bf(b) << 16);
}
__device__ __forceinline__ float bflo(unsigned p) { return __uint_as_float(p << 16); }
__device__ __forceinline__ float bfhi(unsigned p) { return __uint_as_float(p & 0xffff0000u); }

// ---------------- FUSED: gemm1 (blocks < G1) || deg_rank (blocks >= G1) ----------------
// gemm1: h1 = x @ W1 (K=128, NC=128), bf16 out + attn1 epilogue. 128 thr, MT=32.
// deg_rank: histogram + rank of dst cols, 4 edges/thread (atomic-with-return ILP).
// The deg waves are ~0% VALU and fill gemm1's latency-stall slots on the same CUs.
__global__ void k_gemm1_deg(const float* __restrict__ A, const float* __restrict__ B,
                            const float* __restrict__ aux, uint2* __restrict__ C,
                            float* __restrict__ es, float* __restrict__ ed,
                            const int* __restrict__ ei, int* __restrict__ deg,
                            unsigned short* __restrict__ rank) {
    constexpr int K = 128, MT = 32;
    __shared__ float As[MT * K];   // 16 KB (deg blocks simply don't touch it)
    if (blockIdx.x >= G1_BLOCKS) {
        // ---- deg_rank body (256 threads) ----
        int t = (blockIdx.x - G1_BLOCKS) * 256 + threadIdx.x;
        int e0 = 4 * t;
        if (e0 >= E_TOT) return;
        int col[4];
        if (e0 + 3 < E_RAW) {
            int4 c4 = ((const int4*)(ei + E_RAW))[t];
            col[0] = c4.x; col[1] = c4.y; col[2] = c4.z; col[3] = c4.w;
        } else {
#pragma unroll
            for (int i = 0; i < 4; ++i) {
                int e = e0 + i;
                col[i] = (e < E_RAW) ? ei[E_RAW + e] : (e - E_RAW);
            }
        }
        unsigned short rk[4];
#pragma unroll
        for (int i = 0; i < 4; ++i)
            rk[i] = (e0 + i < E_TOT) ? (unsigned short)atomicAdd(&deg[col[i]], 1) : (unsigned short)0;
        if (e0 + 3 < E_TOT) {
            ushort4 v; v.x = rk[0]; v.y = rk[1]; v.z = rk[2]; v.w = rk[3];
            ((ushort4*)rank)[t] = v;
        } else {
#pragma unroll
            for (int i = 0; i < 4; ++i)
                if (e0 + i < E_TOT) rank[e0 + i] = rk[i];
        }
        return;
    }
    // ---- gemm1 body (first 128 threads of the block do the work) ----
    int t = threadIdx.x;
    if (t >= 128) return;
    int m0 = blockIdx.x * MT;
    int g = t >> 5, l = t & 31;
    int rows = min(MT, N_NODES - m0);
    const float4* A4 = (const float4*)(A + (size_t)m0 * K);
    float4* S4 = (float4*)As;
    for (int i = t; i < rows * (K / 4); i += 128) S4[i] = A4[i];
    __syncthreads();
    float acc[8][4];
#pragma unroll
    for (int r = 0; r < 8; ++r)
#pragma unroll
        for (int c = 0; c < 4; ++c) acc[r][c] = 0.f;
    const float4* B4 = (const float4*)B;   // row k = 32 float4
    float4 b0 = B4[0 * 32 + l], b1 = B4[1 * 32 + l], b2 = B4[2 * 32 + l], b3 = B4[3 * 32 + l];
    for (int kk = 0; kk < K / 4 - 1; ++kk) {
        float4 c0 = B4[(4 * kk + 4) * 32 + l];
        float4 c1 = B4[(4 * kk + 5) * 32 + l];
        float4 c2 = B4[(4 * kk + 6) * 32 + l];
        float4 c3 = B4[(4 * kk + 7) * 32 + l];
#pragma unroll
        for (int r = 0; r < 8; ++r) {
            float4 a = ((const float4*)(As + (g * 8 + r) * K))[kk];
            acc[r][0] = fmaf(a.x, b0.x, fmaf(a.y, b1.x, fmaf(a.z, b2.x, fmaf(a.w, b3.x, acc[r][0]))));
            acc[r][1] = fmaf(a.x, b0.y, fmaf(a.y, b1.y, fmaf(a.z, b2.y, fmaf(a.w, b3.y, acc[r][1]))));
            acc[r][2] = fmaf(a.x, b0.z, fmaf(a.y, b1.z, fmaf(a.z, b2.z, fmaf(a.w, b3.z, acc[r][2]))));
            acc[r][3] = fmaf(a.x, b0.w, fmaf(a.y, b1.w, fmaf(a.z, b2.w, fmaf(a.w, b3.w, acc[r][3]))));
        }
        b0 = c0; b1 = c1; b2 = c2; b3 = c3;
    }
    {
        int kk = K / 4 - 1;
#pragma unroll
        for (int r = 0; r < 8; ++r) {
            float4 a = ((const float4*)(As + (g * 8 + r) * K))[kk];
            acc[r][0] = fmaf(a.x, b0.x, fmaf(a.y, b1.x, fmaf(a.z, b2.x, fmaf(a.w, b3.x, acc[r][0]))));
            acc[r][1] = fmaf(a.x, b0.y, fmaf(a.y, b1.y, fmaf(a.z, b2.y, fmaf(a.w, b3.y, acc[r][1]))));
            acc[r][2] = fmaf(a.x, b0.z, fmaf(a.y, b1.z, fmaf(a.z, b2.z, fmaf(a.w, b3.z, acc[r][2]))));
            acc[r][3] = fmaf(a.x, b0.w, fmaf(a.y, b1.w, fmaf(a.z, b2.w, fmaf(a.w, b3.w, acc[r][3]))));
        }
    }
#pragma unroll
    for (int r = 0; r < 8; ++r) {
        int row = m0 + g * 8 + r;
        if (row < N_NODES) {
            uint2 v; v.x = pack2(acc[r][0], acc[r][1]); v.y = pack2(acc[r][2], acc[r][3]);
            C[(size_t)row * 32 + l] = v;
        }
    }
    int h = l >> 3, f0 = 4 * (l & 7);
    float al0 = aux[h * 64 + f0], al1 = aux[h * 64 + f0 + 1], al2 = aux[h * 64 + f0 + 2], al3 = aux[h * 64 + f0 + 3];
    float ar0 = aux[h * 64 + 32 + f0], ar1 = aux[h * 64 + 32 + f0 + 1], ar2 = aux[h * 64 + 32 + f0 + 2], ar3 = aux[h * 64 + 32 + f0 + 3];
#pragma unroll
    for (int r = 0; r < 8; ++r) {
        float pl = acc[r][0] * al0 + acc[r][1] * al1 + acc[r][2] * al2 + acc[r][3] * al3;
        float pr = acc[r][0] * ar0 + acc[r][1] * ar1 + acc[r][2] * ar2 + acc[r][3] * ar3;
#pragma unroll
        for (int mask = 4; mask; mask >>= 1) { pl += __shfl_xor(pl, mask); pr += __shfl_xor(pr, mask); }
        if ((l & 7) == 0) {
            int row = m0 + g * 8 + r;
            if (row < N_NODES) { es[row * 4 + h] = pl; ed[row * 4 + h] = pr; }
        }
    }
}

__global__ void k_scan1(const int* __restrict__ deg, int* __restrict__ off, int* __restrict__ blksum) {
    __shared__ int sh[1024];
    int b = blockIdx.x;
    int i = b * 1024 + threadIdx.x;
    int v = (i < N_NODES) ? deg[i] : 0;
    sh[threadIdx.x] = v;
    __syncthreads();
    for (int ofs = 1; ofs < 1024; ofs <<= 1) {
        int t = (threadIdx.x >= ofs) ? sh[threadIdx.x - ofs] : 0;
        __syncthreads();
        sh[threadIdx.x] += t;
        __syncthreads();
    }
    if (i < N_NODES) off[i] = sh[threadIdx.x] - v;
    if (threadIdx.x == 1023) blksum[b] = sh[1023];
}

__global__ void k_scan2(const int* __restrict__ blksum, int* __restrict__ blkoff, int* __restrict__ off) {
    int l = threadIdx.x & 63;
    int v = (l < NBLK) ? blksum[l] : 0;
    int incl = v;
    for (int ofs = 1; ofs < 64; ofs <<= 1) {
        int t = __shfl_up(incl, ofs);
        if (l >= ofs) incl += t;
    }
    if (l < NBLK) blkoff[l] = incl - v;
    if (l == 63) off[N_NODES] = incl;
}

__global__ void k_scan3(int* __restrict__ off, const int* __restrict__ blkoff) {
    int i = blockIdx.x * blockDim.x + threadIdx.x;
    if (i >= N_NODES) return;
    off[i] += blkoff[i >> 10];
}

// atomic-free scatter: position = off[col] + rank[e]
__global__ void k_scatter2(const int* __restrict__ ei, const int* __restrict__ off,
                           const unsigned short* __restrict__ rank,
                           unsigned short* __restrict__ srcs) {
    int t = blockIdx.x * blockDim.x + threadIdx.x;
    int e0 = 4 * t;
    if (e0 >= E_TOT) return;
    int row[4], col[4], rk[4];
    if (e0 + 3 < E_TOT && e0 + 3 < E_RAW) {
        int4 r4 = ((const int4*)ei)[t];
        int4 c4 = ((const int4*)(ei + E_RAW))[t];
        ushort4 k4 = ((const ushort4*)rank)[t];
        row[0] = r4.x; row[1] = r4.y; row[2] = r4.z; row[3] = r4.w;
        col[0] = c4.x; col[1] = c4.y; col[2] = c4.z; col[3] = c4.w;
        rk[0] = k4.x; rk[1] = k4.y; rk[2] = k4.z; rk[3] = k4.w;
    } else {
#pragma unroll
        for (int i = 0; i < 4; ++i) {
            int e = e0 + i;
            if (e < E_RAW) { row[i] = ei[e]; col[i] = ei[E_RAW + e]; }
            else { row[i] = e - E_RAW; col[i] = row[i]; }
            rk[i] = (e < E_TOT) ? rank[e] : 0;
        }
    }
#pragma unroll
    for (int i = 0; i < 4; ++i)
        if (e0 + i < E_TOT) srcs[off[col[i]] + rk[i]] = (unsigned short)row[i];
}

// ---------------- GEMM 2/3: NC=64 ----------------
template<int K, int EPI>
__global__ void k_gemm23(const float* __restrict__ A, const float* __restrict__ B,
                         const float* __restrict__ aux, void* __restrict__ Cv,
                         float* __restrict__ es, float* __restrict__ ed) {
    constexpr int MT = 32;
    __shared__ float As[MT * K];
    int m0 = blockIdx.x * MT;
    int t = threadIdx.x, g = t >> 4, l = t & 15;
    int rows = min(MT, N_NODES - m0);
    const float4* A4 = (const float4*)(A + (size_t)m0 * K);
    float4* S4 = (float4*)As;
    for (int i = t; i < rows * (K / 4); i += 64) S4[i] = A4[i];
    __syncthreads();
    float acc[8][4];
#pragma unroll
    for (int r = 0; r < 8; ++r)
#pragma unroll
        for (int c = 0; c < 4; ++c) acc[r][c] = 0.f;
    const float4* B4 = (const float4*)B;   // row k = 16 float4
    for (int kk = 0; kk < K / 4; ++kk) {
        float4 b0 = B4[(4 * kk + 0) * 16 + l];
        float4 b1 = B4[(4 * kk + 1) * 16 + l];
        float4 b2 = B4[(4 * kk + 2) * 16 + l];
        float4 b3 = B4[(4 * kk + 3) * 16 + l];
#pragma unroll
        for (int r = 0; r < 8; ++r) {
            float4 a = ((const float4*)(As + (g * 8 + r) * K))[kk];
            acc[r][0] = fmaf(a.x, b0.x, fmaf(a.y, b1.x, fmaf(a.z, b2.x, fmaf(a.w, b3.x, acc[r][0]))));
            acc[r][1] = fmaf(a.x, b0.y, fmaf(a.y, b1.y, fmaf(a.z, b2.y, fmaf(a.w, b3.y, acc[r][1]))));
            acc[r][2] = fmaf(a.x, b0.z, fmaf(a.y, b1.z, fmaf(a.z, b2.z, fmaf(a.w, b3.z, acc[r][2]))));
            acc[r][3] = fmaf(a.x, b0.w, fmaf(a.y, b1.w, fmaf(a.z, b2.w, fmaf(a.w, b3.w, acc[r][3]))));
        }
    }
    if (EPI == 2) {
        uint2* C = (uint2*)Cv;
        float al0 = aux[4 * l], al1 = aux[4 * l + 1], al2 = aux[4 * l + 2], al3 = aux[4 * l + 3];
        float ar0 = aux[64 + 4 * l], ar1 = aux[64 + 4 * l + 1], ar2 = aux[64 + 4 * l + 2], ar3 = aux[64 + 4 * l + 3];
#pragma unroll
        for (int r = 0; r < 8; ++r) {
            int row = m0 + g * 8 + r;
            float pl = acc[r][0] * al0 + acc[r][1] * al1 + acc[r][2] * al2 + acc[r][3] * al3;
            float pr = acc[r][0] * ar0 + acc[r][1] * ar1 + acc[r][2] * ar2 + acc[r][3] * ar3;
#pragma unroll
            for (int mask = 8; mask; mask >>= 1) { pl += __shfl_xor(pl, mask); pr += __shfl_xor(pr, mask); }
            if (row < N_NODES) {
                uint2 v; v.x = pack2(acc[r][0], acc[r][1]); v.y = pack2(acc[r][2], acc[r][3]);
                C[(size_t)row * 16 + l] = v;
                if (l == 0) { es[row] = pl; ed[row] = pr; }
            }
        }
    } else {
        float4* C = (float4*)Cv;
        float4 bv = ((const float4*)aux)[l];
#pragma unroll
        for (int r = 0; r < 8; ++r) {
            int row = m0 + g * 8 + r;
            if (row < N_NODES) {
                float4 v;
                v.x = acc[r][0] + bv.x; v.y = acc[r][1] + bv.y;
                v.z = acc[r][2] + bv.z; v.w = acc[r][3] + bv.w;
                C[(size_t)row * 16 + l] = v;
            }
        }
    }
}

// ---------------- layer-1 fused softmax+aggregate: one wave per node ----------------
__global__ void k_agg1(const unsigned* __restrict__ h1b, const float* __restrict__ es,
                       const float* __restrict__ ed, const int* __restrict__ off,
                       const unsigned short* __restrict__ srcs, float* __restrict__ out1) {
    int n = blockIdx.x * (blockDim.x >> 6) + (threadIdx.x >> 6);
    int lane = threadIdx.x & 63;
    if (n >= N_NODES) return;
    int myh = lane & 3;
    float edh = ed[n * 4 + myh];
    int hc = lane >> 4;
    int s = off[n], e = off[n + 1];
    int jj = lane >> 2;
    float ax = 0.f, ay = 0.f, psum = 0.f;
    for (int base = s; base < e; base += 16) {
        int cnt = e - base;
        int srcj = 0;
        float w = 0.f;
        if (jj < cnt) {
            srcj = srcs[base + jj];
            w = __expf(lrelu(es[srcj * 4 + myh] + edh));
        }
        psum += w;
        unsigned pv[16];
        float wv[16];
#pragma unroll
        for (int j2 = 0; j2 < 16; ++j2) {
            int src = __shfl(srcj, j2 * 4);
            wv[j2] = __shfl(w, j2 * 4 + hc);
            pv[j2] = h1b[(size_t)src * 64 + lane];
        }
#pragma unroll
        for (int j2 = 0; j2 < 16; ++j2) {
            ax = fmaf(bflo(pv[j2]), wv[j2], ax);
            ay = fmaf(bfhi(pv[j2]), wv[j2], ay);
        }
    }
#pragma unroll
    for (int mask = 4; mask <= 32; mask <<= 1) psum += __shfl_xor(psum, mask);
    float inv = 1.f / __shfl(psum, hc);
    float2 o;
    o.x = fmaxf(ax * inv, 0.f);
    o.y = fmaxf(ay * inv, 0.f);
    ((float2*)out1)[(size_t)n * 64 + lane] = o;
}

// ---------------- layer-2 fused softmax+aggregate: half-wave per node ----------------
__global__ void k_agg2(const unsigned* __restrict__ h2b, const float* __restrict__ es,
                       const float* __restrict__ ed, const int* __restrict__ off,
                       const unsigned short* __restrict__ srcs, float* __restrict__ outv) {
    int n = blockIdx.x * (blockDim.x >> 5) + (threadIdx.x >> 5);
    int l = threadIdx.x & 31;
    int hb = threadIdx.x & 32;
    if (n >= N_NODES) return;
    float edv = ed[n];
    int s = off[n], e = off[n + 1];
    const uint2* gp = (const uint2*)h2b;
    int l16 = l & 15;
    int sb0 = (l >> 4) * 2;
    float a0 = 0.f, a1 = 0.f, a2 = 0.f, a3 = 0.f, psum = 0.f;
    for (int base = s; base < e; base += 32) {
        int cnt = e - base;
        int srcj = 0;
        float w = 0.f;
        if (l < cnt) {
            srcj = srcs[base + l];
            w = __expf(lrelu(es[srcj] + edv));
        }
        psum += w;
#pragma unroll
        for (int sub = 0; sub < 2; ++sub) {
            uint2 pv[8];
            float wv[8];
#pragma unroll
            for (int j = 0; j < 8; ++j) {
                int lsrc = hb + (sb0 + sub) * 8 + j;
                int src = __shfl(srcj, lsrc);
                wv[j] = __shfl(w, lsrc);
                pv[j] = gp[(size_t)src * 16 + l16];
            }
#pragma unroll
            for (int j = 0; j < 8; ++j) {
                a0 = fmaf(bflo(pv[j].x), wv[j], a0);
                a1 = fmaf(bfhi(pv[j].x), wv[j], a1);
                a2 = fmaf(bflo(pv[j].y), wv[j], a2);
                a3 = fmaf(bfhi(pv[j].y), wv[j], a3);
            }
        }
    }
#pragma unroll
    for (int mask = 1; mask <= 16; mask <<= 1) psum += __shfl_xor(psum, mask);
    float inv = 1.f / psum;
    a0 += __shfl_xor(a0, 16); a1 += __shfl_xor(a1, 16);
    a2 += __shfl_xor(a2, 16); a3 += __shfl_xor(a3, 16);
    if (l < 16) {
        float4 o;
        o.x = a0 * inv; o.y = a1 * inv; o.z = a2 * inv; o.w = a3 * inv;
        ((float4*)outv)[(size_t)n * 16 + l16] = o;
    }
}

extern "C" void kernel_launch(void* const* d_in, const int* in_sizes, int n_in,
                              void* d_out, int out_size, void* d_ws, size_t ws_size,
                              hipStream_t stream) {
    const float* x     = (const float*)d_in[0];
    const int*   ei    = (const int*)d_in[1];
    const float* W1    = (const float*)d_in[2];
    const float* attn1 = (const float*)d_in[3];
    const float* W2    = (const float*)d_in[4];
    const float* attn2 = (const float*)d_in[5];
    const float* headW = (const float*)d_in[6];
    const float* headb = (const float*)d_in[7];
    float* out = (float*)d_out;

    char* ws = (char*)d_ws;
    size_t o = 0;
    auto alloc = [&](size_t bytes) -> void* {
        o = (o + 255) & ~(size_t)255;
        void* p = ws + o;
        o += bytes;
        return p;
    };
    unsigned*       h1b    = (unsigned*)alloc((size_t)N_NODES * 128 * 2);
    float*          out1   = (float*)alloc((size_t)N_NODES * 128 * 4);
    unsigned*       h2b    = (unsigned*)alloc((size_t)N_NODES * 64 * 2);
    float*          h2agg  = (float*)alloc((size_t)N_NODES * 64 * 4);
    float*          e1s    = (float*)alloc((size_t)N_NODES * 4 * 4);
    float*          e1d    = (float*)alloc((size_t)N_NODES * 4 * 4);
    float*          e2s    = (float*)alloc((size_t)N_NODES * 4);
    float*          e2d    = (float*)alloc((size_t)N_NODES * 4);
    int*            deg    = (int*)alloc((size_t)N_NODES * 4);
    int*            off    = (int*)alloc((size_t)(N_NODES + 1) * 4);
    unsigned short* rank   = (unsigned short*)alloc((size_t)E_TOT * 2);
    unsigned short* srcs   = (unsigned short*)alloc((size_t)E_TOT * 2);
    int*            blksum = (int*)alloc((size_t)NBLK * 4);
    int*            blkoff = (int*)alloc((size_t)NBLK * 4);

    // fused: gemm1 (+attn1 epilogue) || deg_rank histogram
    (void)hipMemsetAsync(deg, 0, (size_t)N_NODES * 4, stream);
    k_gemm1_deg<<<G1_BLOCKS + G2_BLOCKS, 256, 0, stream>>>(
        x, W1, attn1, (uint2*)h1b, e1s, e1d, ei, deg, rank);

    // CSR finalize
    k_scan1<<<NBLK, 1024, 0, stream>>>(deg, off, blksum);
    k_scan2<<<1, 64, 0, stream>>>(blksum, blkoff, off);
    k_scan3<<<(N_NODES + 255) / 256, 256, 0, stream>>>(off, blkoff);
    k_scatter2<<<(E_TOT / 4 + 255) / 256, 256, 0, stream>>>(ei, off, rank, srcs);

    // layer 1 aggregate
    k_agg1<<<N_NODES / 4, 256, 0, stream>>>(h1b, e1s, e1d, off, srcs, out1);

    // layer 2
    k_gemm23<128, 2><<<(N_NODES + 31) / 32, 64, 0, stream>>>(out1, W2, attn2, h2b, e2s, e2d);
    k_agg2<<<N_NODES / 8, 256, 0, stream>>>(h2b, e2s, e2d, off, srcs, h2agg);

    // head
    k_gemm23<64, 3><<<(N_NODES + 31) / 32, 64, 0, stream>>>(h2agg, headW, headb, out, nullptr, nullptr);
}